// Round 5
// baseline (381.321 us; speedup 1.0000x reference)
//
#include <hip/hip_runtime.h>
#include <hip/hip_bf16.h>

#define N_NODES 20000
#define E_EDGES 320000

typedef __attribute__((ext_vector_type(8))) short s8v;
typedef __attribute__((ext_vector_type(4))) float f4v;

__device__ __forceinline__ float lrelu(float v){ return v > 0.f ? v : 0.2f * v; }

// round-to-nearest-even f32 -> bf16 (bit trick)
__device__ __forceinline__ unsigned short bfhi(float v){
  union{float f; unsigned u;} a; a.f = v;
  unsigned r = a.u + 0x7FFFu + ((a.u >> 16) & 1u);
  return (unsigned short)(r >> 16);
}
__device__ __forceinline__ float bf2f(unsigned short h){
  union{unsigned u; float f;} a; a.u = ((unsigned)h) << 16; return a.f;
}

// split pair (v0,v1) into packed-bf16 hi word and lo word (RNE)
__device__ __forceinline__ void split2(float v0, float v1, unsigned& hu, unsigned& lu){
  __hip_bfloat162 h2 = __float22bfloat162_rn(make_float2(v0, v1));
  unsigned h; __builtin_memcpy(&h, &h2, 4);
  union{unsigned u; float f;} c0, c1;
  c0.u = h << 16;
  c1.u = h & 0xFFFF0000u;
  __hip_bfloat162 l2 = __float22bfloat162_rn(make_float2(v0 - c0.f, v1 - c1.f));
  unsigned l; __builtin_memcpy(&l, &l2, 4);
  hu = h; lu = l;
}

// ---------------- CSR build ----------------
__global__ __launch_bounds__(256) void k_count(const int* __restrict__ dst, int* __restrict__ deg, int E){
  int e = blockIdx.x * 256 + threadIdx.x;
  if (e < E) atomicAdd(&deg[dst[e]], 1);
}

__global__ __launch_bounds__(256) void k_scan(const int* __restrict__ deg, int* __restrict__ off,
                                              int* __restrict__ cur, int n){
  __shared__ int part[256];
  __shared__ int base[257];
  int tid = threadIdx.x;
  int chunk = (n + 255) / 256;
  int st = tid * chunk;
  int en = st + chunk; if (en > n) en = n;
  int s = 0;
  for (int i = st; i < en; ++i) s += deg[i];
  part[tid] = s;
  __syncthreads();
  if (tid == 0){
    int a = 0;
    for (int i = 0; i < 256; ++i){ base[i] = a; a += part[i]; }
    base[256] = a;
  }
  __syncthreads();
  int a = base[tid];
  for (int i = st; i < en; ++i){ off[i] = a; cur[i] = 0; a += deg[i]; }
  if (tid == 0) off[n] = base[256];
}

__global__ __launch_bounds__(256) void k_fill(const int* __restrict__ src, const int* __restrict__ dst,
                       const int* __restrict__ ety, const float* __restrict__ ew,
                       const int* __restrict__ off, int* __restrict__ cur,
                       int* __restrict__ csrc, int* __restrict__ cet, float* __restrict__ cw, int E){
  int e = blockIdx.x * 256 + threadIdx.x;
  if (e < E){
    int d = dst[e];
    int p = atomicAdd(&cur[d], 1);
    int i = off[d] + p;
    csrc[i] = src[e];
    cet[i]  = ety[e];
    cw[i]   = ew[e];
  }
}

// ---------------- weight prep: W[K][256] f32 -> Bp hi/lo bf16, layout [kt][n][32kk] ----------------
__global__ __launch_bounds__(64) void k_prep(const float* __restrict__ W, unsigned short* __restrict__ Bp, int K){
  int kt = blockIdx.x;
  int n  = blockIdx.y * 64 + threadIdx.x;
  unsigned short hi[32], lo[32];
#pragma unroll
  for (int kk = 0; kk < 32; ++kk){
    float v = W[(size_t)(kt * 32 + kk) * 256 + n];   // coalesced over n
    unsigned short h = bfhi(v);
    hi[kk] = h;
    lo[kk] = bfhi(v - bf2f(h));
  }
  size_t plane = (size_t)(K >> 5) * 256 * 32;
  size_t b = ((size_t)kt * 256 + n) * 32;
#pragma unroll
  for (int kk = 0; kk < 32; ++kk){
    Bp[b + kk]         = hi[kk];
    Bp[plane + b + kk] = lo[kk];
  }
}

// ---------------- LDS-free split-bf16 MFMA GEMM ----------------
// C[M][256] = A[M][K] @ B. Block 256 thr = 4 waves; wave w: rows m0+w*32..+31, cols n0..n0+63.
// A: f32 (PERM: xc permutation/scale, K fixed 896), split hi/lo in-register.
// B: pre-split frag-ordered Bp, loaded straight into MFMA B-fragments (no LDS anywhere).
// ATT: per-block cols = one head; fold a_src/a_dst projection into epilogue.
template<int KT, bool PERM, bool EPI, bool ATT>
__global__ __launch_bounds__(256) void k_mm(
    const float* __restrict__ A, const unsigned short* __restrict__ Bp,
    const float* __restrict__ bias, float* __restrict__ C,
    const float* __restrict__ attS, const float* __restrict__ attD,
    float* __restrict__ aS, float* __restrict__ aD, int M)
{
  constexpr int K = KT * 32;
  const int tid  = threadIdx.x;
  const int lane = tid & 63;
  const int w    = tid >> 6;
  const int l15  = lane & 15;
  const int kg   = lane >> 4;
  const int m0   = blockIdx.x * 128;
  const int n0   = blockIdx.y * 64;
  const size_t planeB = (size_t)KT * 256 * 32;

  f4v acc[2][4];
#pragma unroll
  for (int f = 0; f < 2; ++f)
#pragma unroll
    for (int g = 0; g < 4; ++g)
#pragma unroll
      for (int r = 0; r < 4; ++r) acc[f][g][r] = 0.f;

  const int rbase = m0 + w * 32 + l15;   // + f*16 -> A-frag row

#pragma unroll 2
  for (int kt = 0; kt < KT; ++kt){
    const int k0 = kt * 32;
    // ---- B fragments straight from global (frag-ordered, fully coalesced, L1/L2-hot) ----
    s8v bh[4], bl[4];
#pragma unroll
    for (int g = 0; g < 4; ++g){
      const unsigned short* bp2 = Bp + ((size_t)kt * 256 + n0 + g * 16 + l15) * 32 + kg * 8;
      bh[g] = *(const s8v*)bp2;
      bl[g] = *(const s8v*)(bp2 + planeB);
    }
    // ---- A fragments: f32 global -> in-register hi/lo split ----
    s8v ah[2], al[2];
#pragma unroll
    for (int f = 0; f < 2; ++f){
      int row = rbase + f * 16;
      float v[8];
      if (row < M){
        if constexpr (PERM){
          int c = k0 + kg * 8;          // 8-chunks never straddle c=128
          const float* sp; float sc;
          if (c < 128){ sp = A + (size_t)row * 896 + (768 + c); sc = 1.f; }
          else        { sp = A + (size_t)row * 896 + (c - 128); sc = 3.f; }
          float4 f0 = *(const float4*)sp;
          float4 f1 = *(const float4*)(sp + 4);
          v[0]=f0.x*sc; v[1]=f0.y*sc; v[2]=f0.z*sc; v[3]=f0.w*sc;
          v[4]=f1.x*sc; v[5]=f1.y*sc; v[6]=f1.z*sc; v[7]=f1.w*sc;
        } else {
          const float* sp = A + (size_t)row * K + k0 + kg * 8;
          float4 f0 = *(const float4*)sp;
          float4 f1 = *(const float4*)(sp + 4);
          v[0]=f0.x; v[1]=f0.y; v[2]=f0.z; v[3]=f0.w;
          v[4]=f1.x; v[5]=f1.y; v[6]=f1.z; v[7]=f1.w;
        }
      } else {
#pragma unroll
        for (int j = 0; j < 8; ++j) v[j] = 0.f;
      }
      union { unsigned u[4]; s8v s; } hv, lv;
#pragma unroll
      for (int p = 0; p < 4; ++p)
        split2(v[2*p], v[2*p+1], hv.u[p], lv.u[p]);
      ah[f] = hv.s; al[f] = lv.s;
    }
    // ---- MFMA: 3-term split product ----
#pragma unroll
    for (int f = 0; f < 2; ++f)
#pragma unroll
      for (int g = 0; g < 4; ++g){
        acc[f][g] = __builtin_amdgcn_mfma_f32_16x16x32_bf16(ah[f], bh[g], acc[f][g], 0, 0, 0);
        acc[f][g] = __builtin_amdgcn_mfma_f32_16x16x32_bf16(ah[f], bl[g], acc[f][g], 0, 0, 0);
        acc[f][g] = __builtin_amdgcn_mfma_f32_16x16x32_bf16(al[f], bh[g], acc[f][g], 0, 0, 0);
      }
  }

  // ---- epilogue: D layout col=lane&15, row=(lane>>4)*4+reg ----
#pragma unroll
  for (int f = 0; f < 2; ++f){
#pragma unroll
    for (int g = 0; g < 4; ++g){
      int col = n0 + g * 16 + l15;
      float bb = EPI ? bias[col] : 0.f;
#pragma unroll
      for (int r = 0; r < 4; ++r){
        int row = m0 + w * 32 + f * 16 + kg * 4 + r;
        if (row < M){
          float v = acc[f][g][r];
          if constexpr (EPI) v = fmaxf(v + bb, 0.f);
          C[(size_t)row * 256 + col] = v;
        }
      }
    }
  }

  if constexpr (ATT){
    // this block's 64 cols == head blockIdx.y; attS/attD flat[256] indexed by col
    float sv[4], dv[4];
#pragma unroll
    for (int g = 0; g < 4; ++g){
      sv[g] = attS[n0 + g * 16 + l15];
      dv[g] = attD[n0 + g * 16 + l15];
    }
    const int head = blockIdx.y;
#pragma unroll
    for (int f = 0; f < 2; ++f){
#pragma unroll
      for (int r = 0; r < 4; ++r){
        float ps = acc[f][0][r]*sv[0] + acc[f][1][r]*sv[1] + acc[f][2][r]*sv[2] + acc[f][3][r]*sv[3];
        float pd = acc[f][0][r]*dv[0] + acc[f][1][r]*dv[1] + acc[f][2][r]*dv[2] + acc[f][3][r]*dv[3];
#pragma unroll
        for (int mm = 1; mm < 16; mm <<= 1){
          ps += __shfl_xor(ps, mm, 64);
          pd += __shfl_xor(pd, mm, 64);
        }
        int row = m0 + w * 32 + f * 16 + kg * 4 + r;
        if (l15 == 0 && row < M){
          aS[(size_t)row * 4 + head] = ps;
          aD[(size_t)row * 4 + head] = pd;
        }
      }
    }
  }
}

// ---------------- first aggregation: h1 = h0 + sum_e (h0[src] + rel[et]*w) ----------------
__global__ __launch_bounds__(256) void k_agg(
    const float* __restrict__ h0, const int* __restrict__ off,
    const int* __restrict__ csrc, const int* __restrict__ cet, const float* __restrict__ cw,
    const float* __restrict__ rel, float* __restrict__ h1, int N)
{
  int n = blockIdx.x * 4 + (threadIdx.x >> 6);
  if (n >= N) return;
  int lane = threadIdx.x & 63;
  int c0 = lane * 4;
  float4 acc = *(const float4*)&h0[(size_t)n * 256 + c0];
  int s0 = off[n], s1 = off[n + 1];
  int e = s0;
  for (; e + 3 < s1; e += 4){
    int sA = csrc[e], sB = csrc[e+1], sC = csrc[e+2], sD = csrc[e+3];
    int tA = cet[e],  tB = cet[e+1],  tC = cet[e+2],  tD = cet[e+3];
    float wA = cw[e], wB = cw[e+1], wC = cw[e+2], wD = cw[e+3];
    float4 hA = *(const float4*)&h0[(size_t)sA * 256 + c0];
    float4 hB = *(const float4*)&h0[(size_t)sB * 256 + c0];
    float4 hC = *(const float4*)&h0[(size_t)sC * 256 + c0];
    float4 hD = *(const float4*)&h0[(size_t)sD * 256 + c0];
    float4 rA = *(const float4*)&rel[(size_t)tA * 256 + c0];
    float4 rB = *(const float4*)&rel[(size_t)tB * 256 + c0];
    float4 rC = *(const float4*)&rel[(size_t)tC * 256 + c0];
    float4 rD = *(const float4*)&rel[(size_t)tD * 256 + c0];
    acc.x += hA.x + hB.x + hC.x + hD.x + rA.x*wA + rB.x*wB + rC.x*wC + rD.x*wD;
    acc.y += hA.y + hB.y + hC.y + hD.y + rA.y*wA + rB.y*wB + rC.y*wC + rD.y*wD;
    acc.z += hA.z + hB.z + hC.z + hD.z + rA.z*wA + rB.z*wB + rC.z*wC + rD.z*wD;
    acc.w += hA.w + hB.w + hC.w + hD.w + rA.w*wA + rB.w*wB + rC.w*wC + rD.w*wD;
  }
  for (; e < s1; ++e){
    int s = csrc[e];
    int t = cet[e];
    float wg = cw[e];
    float4 hv = *(const float4*)&h0[(size_t)s * 256 + c0];
    float4 rv = *(const float4*)&rel[(size_t)t * 256 + c0];
    acc.x += hv.x + rv.x * wg;
    acc.y += hv.y + rv.y * wg;
    acc.z += hv.z + rv.z * wg;
    acc.w += hv.w + rv.w * wg;
  }
  *(float4*)&h1[(size_t)n * 256 + c0] = acc;
}

// ---------------- GAT edge softmax + aggregate (self-loop included) ----------------
__global__ __launch_bounds__(256) void k_gat(
    const float* __restrict__ xh, const float* __restrict__ aS, const float* __restrict__ aD,
    const int* __restrict__ off, const int* __restrict__ csrc,
    const float* __restrict__ bias, float* __restrict__ hout, int N)
{
  int n = blockIdx.x * 4 + (threadIdx.x >> 6);
  if (n >= N) return;
  int lane = threadIdx.x & 63;
  int head = lane >> 4;
  int c0 = lane * 4;
  int s0 = off[n], s1 = off[n + 1];

  float ad0, ad1, ad2, ad3;
  { float4 t = *(const float4*)&aD[(size_t)n * 4]; ad0 = t.x; ad1 = t.y; ad2 = t.z; ad3 = t.w; }
  float q0, q1, q2, q3;  // running max per head (init with self-loop)
  { float4 t = *(const float4*)&aS[(size_t)n * 4];
    q0 = lrelu(t.x + ad0); q1 = lrelu(t.y + ad1); q2 = lrelu(t.z + ad2); q3 = lrelu(t.w + ad3); }

  for (int base = s0; base < s1; base += 64){
    int e = base + lane;
    if (e < s1){
      int s = csrc[e];
      float4 av = *(const float4*)&aS[(size_t)s * 4];
      q0 = fmaxf(q0, lrelu(av.x + ad0));
      q1 = fmaxf(q1, lrelu(av.y + ad1));
      q2 = fmaxf(q2, lrelu(av.z + ad2));
      q3 = fmaxf(q3, lrelu(av.w + ad3));
    }
  }
#pragma unroll
  for (int mm = 1; mm < 64; mm <<= 1){
    q0 = fmaxf(q0, __shfl_xor(q0, mm, 64));
    q1 = fmaxf(q1, __shfl_xor(q1, mm, 64));
    q2 = fmaxf(q2, __shfl_xor(q2, mm, 64));
    q3 = fmaxf(q3, __shfl_xor(q3, mm, 64));
  }
  float adh = head == 0 ? ad0 : (head == 1 ? ad1 : (head == 2 ? ad2 : ad3));
  float mh  = head == 0 ? q0  : (head == 1 ? q1  : (head == 2 ? q2  : q3));

  float ash = aS[(size_t)n * 4 + head];
  float ex = __expf(lrelu(ash + adh) - mh);
  float den = ex;
  float4 xv = *(const float4*)&xh[(size_t)n * 256 + c0];
  float4 acc;
  acc.x = ex * xv.x; acc.y = ex * xv.y; acc.z = ex * xv.z; acc.w = ex * xv.w;

  int e = s0;
  for (; e + 3 < s1; e += 4){
    int sA = csrc[e], sB = csrc[e+1], sC = csrc[e+2], sD = csrc[e+3];
    float aA = aS[(size_t)sA * 4 + head];
    float aB = aS[(size_t)sB * 4 + head];
    float aC = aS[(size_t)sC * 4 + head];
    float aD2 = aS[(size_t)sD * 4 + head];
    float4 xA = *(const float4*)&xh[(size_t)sA * 256 + c0];
    float4 xB = *(const float4*)&xh[(size_t)sB * 256 + c0];
    float4 xC = *(const float4*)&xh[(size_t)sC * 256 + c0];
    float4 xD = *(const float4*)&xh[(size_t)sD * 256 + c0];
    float eA = __expf(lrelu(aA + adh) - mh);
    float eB = __expf(lrelu(aB + adh) - mh);
    float eC = __expf(lrelu(aC + adh) - mh);
    float eD = __expf(lrelu(aD2 + adh) - mh);
    den += eA + eB + eC + eD;
    acc.x = fmaf(eA, xA.x, fmaf(eB, xB.x, fmaf(eC, xC.x, fmaf(eD, xD.x, acc.x))));
    acc.y = fmaf(eA, xA.y, fmaf(eB, xB.y, fmaf(eC, xC.y, fmaf(eD, xD.y, acc.y))));
    acc.z = fmaf(eA, xA.z, fmaf(eB, xB.z, fmaf(eC, xC.z, fmaf(eD, xD.z, acc.z))));
    acc.w = fmaf(eA, xA.w, fmaf(eB, xB.w, fmaf(eC, xC.w, fmaf(eD, xD.w, acc.w))));
  }
  for (; e < s1; ++e){
    int s = csrc[e];
    float a  = aS[(size_t)s * 4 + head];
    float e2 = __expf(lrelu(a + adh) - mh);
    den += e2;
    float4 x2 = *(const float4*)&xh[(size_t)s * 256 + c0];
    acc.x = fmaf(e2, x2.x, acc.x);
    acc.y = fmaf(e2, x2.y, acc.y);
    acc.z = fmaf(e2, x2.z, acc.z);
    acc.w = fmaf(e2, x2.w, acc.w);
  }
  float inv = 1.f / den;
  float4 bb = *(const float4*)&bias[c0];
  float4 o;
  o.x = acc.x * inv + bb.x;
  o.y = acc.y * inv + bb.y;
  o.z = acc.z * inv + bb.z;
  o.w = acc.w * inv + bb.w;
  *(float4*)&hout[(size_t)n * 256 + c0] = o;
}

// ---------------- final score ----------------
__global__ __launch_bounds__(256) void k_score(
    const float* __restrict__ h, const float* __restrict__ Wo, const float* __restrict__ bo,
    float* __restrict__ out, int N)
{
  int n = blockIdx.x * 4 + (threadIdx.x >> 6);
  if (n >= N) return;
  int lane = threadIdx.x & 63;
  int c0 = lane * 4;
  float4 hv = *(const float4*)&h[(size_t)n * 256 + c0];
  float4 wv = *(const float4*)&Wo[c0];
  float p = hv.x * wv.x + hv.y * wv.y + hv.z * wv.z + hv.w * wv.w;
#pragma unroll
  for (int mm = 1; mm < 64; mm <<= 1) p += __shfl_xor(p, mm, 64);
  if (lane == 0) out[n] = p + bo[0];
}

extern "C" void kernel_launch(void* const* d_in, const int* in_sizes, int n_in,
                              void* d_out, int out_size, void* d_ws, size_t ws_size,
                              hipStream_t stream)
{
  const float* x   = (const float*)d_in[0];
  const int*   ei  = (const int*)  d_in[1];
  const int*   ety = (const int*)  d_in[2];
  const float* ew  = (const float*)d_in[3];
  const float* rel = (const float*)d_in[4];
  const float* Wp  = (const float*)d_in[5];
  const float* bp  = (const float*)d_in[6];
  const float* W1  = (const float*)d_in[7];
  const float* as1 = (const float*)d_in[8];
  const float* ad1 = (const float*)d_in[9];
  const float* b1  = (const float*)d_in[10];
  const float* W2  = (const float*)d_in[11];
  const float* as2 = (const float*)d_in[12];
  const float* ad2 = (const float*)d_in[13];
  const float* b2  = (const float*)d_in[14];
  const float* Wo  = (const float*)d_in[15];
  const float* bo  = (const float*)d_in[16];
  float* out = (float*)d_out;

  const int N = N_NODES, E = E_EDGES;
  char* w = (char*)d_ws;
  size_t o = 0;
  auto alloc = [&](size_t bytes) -> char* {
    char* p = w + o;
    o = (o + bytes + 255) & ~(size_t)255;
    return p;
  };
  float* h0  = (float*)alloc((size_t)N * 256 * 4);
  float* h1  = (float*)alloc((size_t)N * 256 * 4);
  float* xh  = (float*)alloc((size_t)N * 256 * 4);
  float* aS  = (float*)alloc((size_t)N * 4 * 4);
  float* aD  = (float*)alloc((size_t)N * 4 * 4);
  int* deg   = (int*)alloc((size_t)N * 4);
  int* offs  = (int*)alloc((size_t)(N + 1) * 4);
  int* cur   = (int*)alloc((size_t)N * 4);
  int* csrc  = (int*)alloc((size_t)E * 4);
  int* cet   = (int*)alloc((size_t)E * 4);
  float* cw  = (float*)alloc((size_t)E * 4);
  unsigned short* BpP = (unsigned short*)alloc((size_t)2 * 896 * 256 * 2);
  unsigned short* Bp1 = (unsigned short*)alloc((size_t)2 * 256 * 256 * 2);
  unsigned short* Bp2 = (unsigned short*)alloc((size_t)2 * 256 * 256 * 2);

  const int* srcp = ei;
  const int* dstp = ei + E;

  hipMemsetAsync(deg, 0, (size_t)N * 4, stream);
  k_count<<<(E + 255) / 256, 256, 0, stream>>>(dstp, deg, E);
  k_scan<<<1, 256, 0, stream>>>(deg, offs, cur, N);
  k_fill<<<(E + 255) / 256, 256, 0, stream>>>(srcp, dstp, ety, ew, offs, cur, csrc, cet, cw, E);

  // weight pre-split into frag-ordered hi/lo planes
  k_prep<<<dim3(896 / 32, 4), 64, 0, stream>>>(Wp, BpP, 896);
  k_prep<<<dim3(256 / 32, 4), 64, 0, stream>>>(W1, Bp1, 256);
  k_prep<<<dim3(256 / 32, 4), 64, 0, stream>>>(W2, Bp2, 256);

  dim3 ggrid((N + 127) / 128, 4);
  int nblk = (N + 3) / 4;

  // h0 = relu(xc @ Wp + bp)
  k_mm<28, true, true, false><<<ggrid, 256, 0, stream>>>(
      x, BpP, bp, h0, nullptr, nullptr, nullptr, nullptr, N);
  // h1 = h0 + sum_in(h0[src] + rel*w)
  k_agg<<<nblk, 256, 0, stream>>>(h0, offs, csrc, cet, cw, rel, h1, N);
  // GAT layer 1 (att projections fused into GEMM epilogue)
  k_mm<8, false, false, true><<<ggrid, 256, 0, stream>>>(
      h1, Bp1, nullptr, xh, as1, ad1, aS, aD, N);
  k_gat<<<nblk, 256, 0, stream>>>(xh, aS, aD, offs, csrc, b1, h1, N);
  // GAT layer 2
  k_mm<8, false, false, true><<<ggrid, 256, 0, stream>>>(
      h1, Bp2, nullptr, xh, as2, ad2, aS, aD, N);
  k_gat<<<nblk, 256, 0, stream>>>(xh, aS, aD, offs, csrc, b2, h1, N);
  // score
  k_score<<<nblk, 256, 0, stream>>>(h1, Wo, bo, out, N);
}

// Round 6
// 289.903 us; speedup vs baseline: 1.3153x; 1.3153x over previous
//
#include <hip/hip_runtime.h>
#include <hip/hip_bf16.h>

#define N_NODES 20000
#define E_EDGES 320000

typedef __attribute__((ext_vector_type(8))) short s8v;
typedef __attribute__((ext_vector_type(4))) float f4v;

__device__ __forceinline__ float lrelu(float v){ return v > 0.f ? v : 0.2f * v; }

__device__ __forceinline__ float bitf(unsigned short u){
  union { unsigned int i; float f; } v; v.i = ((unsigned int)u) << 16; return v.f;
}
__device__ __forceinline__ float4 bf4(const unsigned short* p){
  ushort4 u = *(const ushort4*)p;
  return make_float4(bitf(u.x), bitf(u.y), bitf(u.z), bitf(u.w));
}
// round-to-nearest-even f32 -> bf16 (bit trick)
__device__ __forceinline__ unsigned short bfhi(float v){
  union{float f; unsigned u;} a; a.f = v;
  unsigned r = a.u + 0x7FFFu + ((a.u >> 16) & 1u);
  return (unsigned short)(r >> 16);
}
__device__ __forceinline__ float bf2f(unsigned short h){
  union{unsigned u; float f;} a; a.u = ((unsigned)h) << 16; return a.f;
}
// split pair (v0,v1) into packed-bf16 hi word and lo word (RNE)
__device__ __forceinline__ void split2(float v0, float v1, unsigned& hu, unsigned& lu){
  __hip_bfloat162 h2 = __float22bfloat162_rn(make_float2(v0, v1));
  unsigned h; __builtin_memcpy(&h, &h2, 4);
  union{unsigned u; float f;} c0, c1;
  c0.u = h << 16;
  c1.u = h & 0xFFFF0000u;
  __hip_bfloat162 l2 = __float22bfloat162_rn(make_float2(v0 - c0.f, v1 - c1.f));
  unsigned l; __builtin_memcpy(&l, &l2, 4);
  hu = h; lu = l;
}

// ---------------- CSR build ----------------
__global__ __launch_bounds__(256) void k_count(const int* __restrict__ dst, int* __restrict__ deg, int E){
  int e = blockIdx.x * 256 + threadIdx.x;
  if (e < E) atomicAdd(&deg[dst[e]], 1);
}

__global__ __launch_bounds__(256) void k_scan(const int* __restrict__ deg, int* __restrict__ off,
                                              int* __restrict__ cur, int n){
  __shared__ int part[256];
  __shared__ int base[257];
  int tid = threadIdx.x;
  int chunk = (n + 255) / 256;
  int st = tid * chunk;
  int en = st + chunk; if (en > n) en = n;
  int s = 0;
  for (int i = st; i < en; ++i) s += deg[i];
  part[tid] = s;
  __syncthreads();
  if (tid == 0){
    int a = 0;
    for (int i = 0; i < 256; ++i){ base[i] = a; a += part[i]; }
    base[256] = a;
  }
  __syncthreads();
  int a = base[tid];
  for (int i = st; i < en; ++i){ off[i] = a; cur[i] = 0; a += deg[i]; }
  if (tid == 0) off[n] = base[256];
}

__global__ __launch_bounds__(256) void k_fill(const int* __restrict__ src, const int* __restrict__ dst,
                       const int* __restrict__ ety, const float* __restrict__ ew,
                       const int* __restrict__ off, int* __restrict__ cur,
                       int* __restrict__ csrc, int* __restrict__ cet, float* __restrict__ cw, int E){
  int e = blockIdx.x * 256 + threadIdx.x;
  if (e < E){
    int d = dst[e];
    int p = atomicAdd(&cur[d], 1);
    int i = off[d] + p;
    csrc[i] = src[e];
    cet[i]  = ety[e];
    cw[i]   = ew[e];
  }
}

// ---------------- weight prep: W[K][256] f32 -> Bp hi/lo bf16, layout [kt][n][32kk] ----------------
__global__ __launch_bounds__(64) void k_prep(const float* __restrict__ W, unsigned short* __restrict__ Bp, int K){
  int kt = blockIdx.x;
  int n  = blockIdx.y * 64 + threadIdx.x;
  unsigned short hi[32], lo[32];
#pragma unroll
  for (int kk = 0; kk < 32; ++kk){
    float v = W[(size_t)(kt * 32 + kk) * 256 + n];   // coalesced over n
    unsigned short h = bfhi(v);
    hi[kk] = h;
    lo[kk] = bfhi(v - bf2f(h));
  }
  size_t plane = (size_t)(K >> 5) * 256 * 32;
  size_t b = ((size_t)kt * 256 + n) * 32;
#pragma unroll
  for (int kk = 0; kk < 32; ++kk){
    Bp[b + kk]         = hi[kk];
    Bp[plane + b + kk] = lo[kk];
  }
}

// ---------------- hybrid split-bf16 MFMA GEMM ----------------
// C[M][256] = A[M][K] @ B.  BM=64 rows x BN=128 cols, 4 waves (2m x 2n), wave tile 32x64.
// A: f32, staged through LDS PRE-SPLIT into hi/lo bf16 (staged once per block, T14 early-issue).
// B: pre-split frag-ordered Bp read straight from global into B-fragments (L2-hot, no LDS).
// PERM: xc column permutation/scale (proj layer).  EPI: +bias, relu.
// CBF: C written as bf16.  ATT: fused a_src/a_dst epilogue (each wave's 64 cols = one head).
template<int KT, bool PERM, bool EPI, bool ATT, bool CBF>
__global__ __launch_bounds__(256) void k_mm(
    const float* __restrict__ A, const unsigned short* __restrict__ Bp,
    const float* __restrict__ bias, void* __restrict__ Cout,
    const float* __restrict__ attS, const float* __restrict__ attD,
    float* __restrict__ aS, float* __restrict__ aD, int M)
{
  constexpr int K = KT * 32;
  __shared__ unsigned short Ah[64 * 40];
  __shared__ unsigned short Al[64 * 40];

  const int tid  = threadIdx.x;
  const int lane = tid & 63;
  const int w    = tid >> 6;
  const int wm   = w >> 1;
  const int wn   = w & 1;
  const int l15  = lane & 15;
  const int kg   = lane >> 4;
  const int m0   = blockIdx.x * 64;
  const int n0   = blockIdx.y * 128;
  const size_t planeB = (size_t)KT * 256 * 32;

  f4v acc[2][4];
#pragma unroll
  for (int f = 0; f < 2; ++f)
#pragma unroll
    for (int g = 0; g < 4; ++g)
#pragma unroll
      for (int r = 0; r < 4; ++r) acc[f][g][r] = 0.f;

  const int arow = tid >> 2;          // 0..63 staged row
  const int aj   = tid & 3;           // k-chunk: akk = aj*8
  const int gr   = m0 + arow;

  auto loadA = [&](float* v, int kt){
    if (gr < M){
      if constexpr (PERM){
        int c = kt * 32 + aj * 8;     // 8-chunks never straddle c=128
        const float* sp; float sc;
        if (c < 128){ sp = A + (size_t)gr * 896 + (768 + c); sc = 1.f; }
        else        { sp = A + (size_t)gr * 896 + (c - 128); sc = 3.f; }
        float4 f0 = *(const float4*)sp;
        float4 f1 = *(const float4*)(sp + 4);
        v[0]=f0.x*sc; v[1]=f0.y*sc; v[2]=f0.z*sc; v[3]=f0.w*sc;
        v[4]=f1.x*sc; v[5]=f1.y*sc; v[6]=f1.z*sc; v[7]=f1.w*sc;
      } else {
        const float* sp = A + (size_t)gr * K + kt * 32 + aj * 8;
        float4 f0 = *(const float4*)sp;
        float4 f1 = *(const float4*)(sp + 4);
        v[0]=f0.x; v[1]=f0.y; v[2]=f0.z; v[3]=f0.w;
        v[4]=f1.x; v[5]=f1.y; v[6]=f1.z; v[7]=f1.w;
      }
    } else {
#pragma unroll
      for (int j = 0; j < 8; ++j) v[j] = 0.f;
    }
  };

  float av[8];
  loadA(av, 0);

  for (int kt = 0; kt < KT; ++kt){
    // ---- split current A chunk, write LDS ----
    {
      union { unsigned u[4]; s8v s; } hv, lv;
#pragma unroll
      for (int p = 0; p < 4; ++p)
        split2(av[2*p], av[2*p+1], hv.u[p], lv.u[p]);
      *(s8v*)&Ah[arow * 40 + aj * 8] = hv.s;
      *(s8v*)&Al[arow * 40 + aj * 8] = lv.s;
    }
    __syncthreads();
    // ---- T14: issue next A chunk loads early (latency hides under B-loads + MFMA) ----
    float nv[8];
    if (kt + 1 < KT) loadA(nv, kt + 1);
    // ---- B fragments straight from global (frag-ordered, L2-hot) ----
    s8v bh[4], bl[4];
#pragma unroll
    for (int g = 0; g < 4; ++g){
      const unsigned short* bp2 = Bp + ((size_t)kt * 256 + n0 + wn * 64 + g * 16 + l15) * 32 + kg * 8;
      bh[g] = *(const s8v*)bp2;
      bl[g] = *(const s8v*)(bp2 + planeB);
    }
    // ---- A fragments from LDS ----
    s8v ah[2], al[2];
#pragma unroll
    for (int f = 0; f < 2; ++f){
      int row = wm * 32 + f * 16 + l15;
      ah[f] = *(const s8v*)&Ah[row * 40 + kg * 8];
      al[f] = *(const s8v*)&Al[row * 40 + kg * 8];
    }
    // ---- MFMA: 3-term split product ----
#pragma unroll
    for (int f = 0; f < 2; ++f)
#pragma unroll
      for (int g = 0; g < 4; ++g){
        acc[f][g] = __builtin_amdgcn_mfma_f32_16x16x32_bf16(ah[f], bh[g], acc[f][g], 0, 0, 0);
        acc[f][g] = __builtin_amdgcn_mfma_f32_16x16x32_bf16(ah[f], bl[g], acc[f][g], 0, 0, 0);
        acc[f][g] = __builtin_amdgcn_mfma_f32_16x16x32_bf16(al[f], bh[g], acc[f][g], 0, 0, 0);
      }
    __syncthreads();
    if (kt + 1 < KT){
#pragma unroll
      for (int j = 0; j < 8; ++j) av[j] = nv[j];
    }
  }

  // ---- epilogue: D layout col=lane&15, row=(lane>>4)*4+reg ----
#pragma unroll
  for (int f = 0; f < 2; ++f){
#pragma unroll
    for (int g = 0; g < 4; ++g){
      int col = n0 + wn * 64 + g * 16 + l15;
      float bb = EPI ? bias[col] : 0.f;
#pragma unroll
      for (int r = 0; r < 4; ++r){
        int row = m0 + wm * 32 + f * 16 + kg * 4 + r;
        if (row < M){
          float v = acc[f][g][r];
          if constexpr (EPI) v = fmaxf(v + bb, 0.f);
          if constexpr (CBF) ((unsigned short*)Cout)[(size_t)row * 256 + col] = bfhi(v);
          else               ((float*)Cout)[(size_t)row * 256 + col] = v;
        }
      }
    }
  }

  if constexpr (ATT){
    // wave's 64 cols = one head: head = (n0 + wn*64)/64
    const int head = (n0 >> 6) + wn;
    float sv[4], dv[4];
#pragma unroll
    for (int g = 0; g < 4; ++g){
      int col = n0 + wn * 64 + g * 16 + l15;
      sv[g] = attS[col];
      dv[g] = attD[col];
    }
#pragma unroll
    for (int f = 0; f < 2; ++f){
#pragma unroll
      for (int r = 0; r < 4; ++r){
        float ps = acc[f][0][r]*sv[0] + acc[f][1][r]*sv[1] + acc[f][2][r]*sv[2] + acc[f][3][r]*sv[3];
        float pd = acc[f][0][r]*dv[0] + acc[f][1][r]*dv[1] + acc[f][2][r]*dv[2] + acc[f][3][r]*dv[3];
#pragma unroll
        for (int mm = 1; mm < 16; mm <<= 1){
          ps += __shfl_xor(ps, mm, 64);
          pd += __shfl_xor(pd, mm, 64);
        }
        int row = m0 + wm * 32 + f * 16 + kg * 4 + r;
        if (l15 == 0 && row < M){
          aS[(size_t)row * 4 + head] = ps;
          aD[(size_t)row * 4 + head] = pd;
        }
      }
    }
  }
}

// ---------------- first aggregation: h1 = h0 + sum_e (h0[src] + rel[et]*w); h0 is bf16 ----------------
__global__ __launch_bounds__(256) void k_agg(
    const unsigned short* __restrict__ h0, const int* __restrict__ off,
    const int* __restrict__ csrc, const int* __restrict__ cet, const float* __restrict__ cw,
    const float* __restrict__ rel, float* __restrict__ h1, int N)
{
  int n = blockIdx.x * 4 + (threadIdx.x >> 6);
  if (n >= N) return;
  int lane = threadIdx.x & 63;
  int c0 = lane * 4;
  float4 acc = bf4(&h0[(size_t)n * 256 + c0]);
  int s0 = off[n], s1 = off[n + 1];
  int e = s0;
  for (; e + 3 < s1; e += 4){
    int sA = csrc[e], sB = csrc[e+1], sC = csrc[e+2], sD = csrc[e+3];
    int tA = cet[e],  tB = cet[e+1],  tC = cet[e+2],  tD = cet[e+3];
    float wA = cw[e], wB = cw[e+1], wC = cw[e+2], wD = cw[e+3];
    float4 hA = bf4(&h0[(size_t)sA * 256 + c0]);
    float4 hB = bf4(&h0[(size_t)sB * 256 + c0]);
    float4 hC = bf4(&h0[(size_t)sC * 256 + c0]);
    float4 hD = bf4(&h0[(size_t)sD * 256 + c0]);
    float4 rA = *(const float4*)&rel[(size_t)tA * 256 + c0];
    float4 rB = *(const float4*)&rel[(size_t)tB * 256 + c0];
    float4 rC = *(const float4*)&rel[(size_t)tC * 256 + c0];
    float4 rD = *(const float4*)&rel[(size_t)tD * 256 + c0];
    acc.x += hA.x + hB.x + hC.x + hD.x + rA.x*wA + rB.x*wB + rC.x*wC + rD.x*wD;
    acc.y += hA.y + hB.y + hC.y + hD.y + rA.y*wA + rB.y*wB + rC.y*wC + rD.y*wD;
    acc.z += hA.z + hB.z + hC.z + hD.z + rA.z*wA + rB.z*wB + rC.z*wC + rD.z*wD;
    acc.w += hA.w + hB.w + hC.w + hD.w + rA.w*wA + rB.w*wB + rC.w*wC + rD.w*wD;
  }
  for (; e < s1; ++e){
    int s = csrc[e];
    int t = cet[e];
    float wg = cw[e];
    float4 hv = bf4(&h0[(size_t)s * 256 + c0]);
    float4 rv = *(const float4*)&rel[(size_t)t * 256 + c0];
    acc.x += hv.x + rv.x * wg;
    acc.y += hv.y + rv.y * wg;
    acc.z += hv.z + rv.z * wg;
    acc.w += hv.w + rv.w * wg;
  }
  *(float4*)&h1[(size_t)n * 256 + c0] = acc;
}

// ---------------- GAT edge softmax + aggregate (self-loop included); xh is bf16 ----------------
// SCORE: fold final h@Wo+bo into the layer-2 epilogue, write out[n] instead of hout.
template<bool SCORE>
__global__ __launch_bounds__(256) void k_gat(
    const unsigned short* __restrict__ xh, const float* __restrict__ aS, const float* __restrict__ aD,
    const int* __restrict__ off, const int* __restrict__ csrc,
    const float* __restrict__ bias, float* __restrict__ hout,
    const float* __restrict__ Wo, const float* __restrict__ bo, float* __restrict__ out, int N)
{
  int n = blockIdx.x * 4 + (threadIdx.x >> 6);
  if (n >= N) return;
  int lane = threadIdx.x & 63;
  int head = lane >> 4;
  int c0 = lane * 4;
  int s0 = off[n], s1 = off[n + 1];

  float ad0, ad1, ad2, ad3;
  { float4 t = *(const float4*)&aD[(size_t)n * 4]; ad0 = t.x; ad1 = t.y; ad2 = t.z; ad3 = t.w; }
  float q0, q1, q2, q3;  // running max per head (init with self-loop)
  { float4 t = *(const float4*)&aS[(size_t)n * 4];
    q0 = lrelu(t.x + ad0); q1 = lrelu(t.y + ad1); q2 = lrelu(t.z + ad2); q3 = lrelu(t.w + ad3); }

  for (int base = s0; base < s1; base += 64){
    int e = base + lane;
    if (e < s1){
      int s = csrc[e];
      float4 av = *(const float4*)&aS[(size_t)s * 4];
      q0 = fmaxf(q0, lrelu(av.x + ad0));
      q1 = fmaxf(q1, lrelu(av.y + ad1));
      q2 = fmaxf(q2, lrelu(av.z + ad2));
      q3 = fmaxf(q3, lrelu(av.w + ad3));
    }
  }
#pragma unroll
  for (int mm = 1; mm < 64; mm <<= 1){
    q0 = fmaxf(q0, __shfl_xor(q0, mm, 64));
    q1 = fmaxf(q1, __shfl_xor(q1, mm, 64));
    q2 = fmaxf(q2, __shfl_xor(q2, mm, 64));
    q3 = fmaxf(q3, __shfl_xor(q3, mm, 64));
  }
  float adh = head == 0 ? ad0 : (head == 1 ? ad1 : (head == 2 ? ad2 : ad3));
  float mh  = head == 0 ? q0  : (head == 1 ? q1  : (head == 2 ? q2  : q3));

  float ash = aS[(size_t)n * 4 + head];
  float ex = __expf(lrelu(ash + adh) - mh);
  float den = ex;
  float4 xv = bf4(&xh[(size_t)n * 256 + c0]);
  float4 acc;
  acc.x = ex * xv.x; acc.y = ex * xv.y; acc.z = ex * xv.z; acc.w = ex * xv.w;

  int e = s0;
  for (; e + 3 < s1; e += 4){
    int sA = csrc[e], sB = csrc[e+1], sC = csrc[e+2], sD = csrc[e+3];
    float aA = aS[(size_t)sA * 4 + head];
    float aB = aS[(size_t)sB * 4 + head];
    float aC = aS[(size_t)sC * 4 + head];
    float aD2 = aS[(size_t)sD * 4 + head];
    float4 xA = bf4(&xh[(size_t)sA * 256 + c0]);
    float4 xB = bf4(&xh[(size_t)sB * 256 + c0]);
    float4 xC = bf4(&xh[(size_t)sC * 256 + c0]);
    float4 xD = bf4(&xh[(size_t)sD * 256 + c0]);
    float eA = __expf(lrelu(aA + adh) - mh);
    float eB = __expf(lrelu(aB + adh) - mh);
    float eC = __expf(lrelu(aC + adh) - mh);
    float eD = __expf(lrelu(aD2 + adh) - mh);
    den += eA + eB + eC + eD;
    acc.x = fmaf(eA, xA.x, fmaf(eB, xB.x, fmaf(eC, xC.x, fmaf(eD, xD.x, acc.x))));
    acc.y = fmaf(eA, xA.y, fmaf(eB, xB.y, fmaf(eC, xC.y, fmaf(eD, xD.y, acc.y))));
    acc.z = fmaf(eA, xA.z, fmaf(eB, xB.z, fmaf(eC, xC.z, fmaf(eD, xD.z, acc.z))));
    acc.w = fmaf(eA, xA.w, fmaf(eB, xB.w, fmaf(eC, xC.w, fmaf(eD, xD.w, acc.w))));
  }
  for (; e < s1; ++e){
    int s = csrc[e];
    float a  = aS[(size_t)s * 4 + head];
    float e2 = __expf(lrelu(a + adh) - mh);
    den += e2;
    float4 x2 = bf4(&xh[(size_t)s * 256 + c0]);
    acc.x = fmaf(e2, x2.x, acc.x);
    acc.y = fmaf(e2, x2.y, acc.y);
    acc.z = fmaf(e2, x2.z, acc.z);
    acc.w = fmaf(e2, x2.w, acc.w);
  }
  float inv = 1.f / den;
  float4 bb = *(const float4*)&bias[c0];
  float4 o;
  o.x = acc.x * inv + bb.x;
  o.y = acc.y * inv + bb.y;
  o.z = acc.z * inv + bb.z;
  o.w = acc.w * inv + bb.w;
  if constexpr (SCORE){
    float4 wv = *(const float4*)&Wo[c0];
    float p = o.x * wv.x + o.y * wv.y + o.z * wv.z + o.w * wv.w;
#pragma unroll
    for (int mm = 1; mm < 64; mm <<= 1) p += __shfl_xor(p, mm, 64);
    if (lane == 0) out[n] = p + bo[0];
  } else {
    *(float4*)&hout[(size_t)n * 256 + c0] = o;
  }
}

extern "C" void kernel_launch(void* const* d_in, const int* in_sizes, int n_in,
                              void* d_out, int out_size, void* d_ws, size_t ws_size,
                              hipStream_t stream)
{
  const float* x   = (const float*)d_in[0];
  const int*   ei  = (const int*)  d_in[1];
  const int*   ety = (const int*)  d_in[2];
  const float* ew  = (const float*)d_in[3];
  const float* rel = (const float*)d_in[4];
  const float* Wp  = (const float*)d_in[5];
  const float* bp  = (const float*)d_in[6];
  const float* W1  = (const float*)d_in[7];
  const float* as1 = (const float*)d_in[8];
  const float* ad1 = (const float*)d_in[9];
  const float* b1  = (const float*)d_in[10];
  const float* W2  = (const float*)d_in[11];
  const float* as2 = (const float*)d_in[12];
  const float* ad2 = (const float*)d_in[13];
  const float* b2  = (const float*)d_in[14];
  const float* Wo  = (const float*)d_in[15];
  const float* bo  = (const float*)d_in[16];
  float* out = (float*)d_out;

  const int N = N_NODES, E = E_EDGES;
  char* w = (char*)d_ws;
  size_t o = 0;
  auto alloc = [&](size_t bytes) -> char* {
    char* p = w + o;
    o = (o + bytes + 255) & ~(size_t)255;
    return p;
  };
  unsigned short* h0b = (unsigned short*)alloc((size_t)N * 256 * 2);  // bf16 h0
  unsigned short* xhb = (unsigned short*)alloc((size_t)N * 256 * 2);  // bf16 xh
  float* h1  = (float*)alloc((size_t)N * 256 * 4);
  float* aS  = (float*)alloc((size_t)N * 4 * 4);
  float* aD  = (float*)alloc((size_t)N * 4 * 4);
  int* deg   = (int*)alloc((size_t)N * 4);
  int* offs  = (int*)alloc((size_t)(N + 1) * 4);
  int* cur   = (int*)alloc((size_t)N * 4);
  int* csrc  = (int*)alloc((size_t)E * 4);
  int* cet   = (int*)alloc((size_t)E * 4);
  float* cw  = (float*)alloc((size_t)E * 4);
  unsigned short* BpP = (unsigned short*)alloc((size_t)2 * 896 * 256 * 2);
  unsigned short* Bp1 = (unsigned short*)alloc((size_t)2 * 256 * 256 * 2);
  unsigned short* Bp2 = (unsigned short*)alloc((size_t)2 * 256 * 256 * 2);

  const int* srcp = ei;
  const int* dstp = ei + E;

  hipMemsetAsync(deg, 0, (size_t)N * 4, stream);
  k_count<<<(E + 255) / 256, 256, 0, stream>>>(dstp, deg, E);
  k_scan<<<1, 256, 0, stream>>>(deg, offs, cur, N);
  k_fill<<<(E + 255) / 256, 256, 0, stream>>>(srcp, dstp, ety, ew, offs, cur, csrc, cet, cw, E);

  // weight pre-split into frag-ordered hi/lo planes
  k_prep<<<dim3(896 / 32, 4), 64, 0, stream>>>(Wp, BpP, 896);
  k_prep<<<dim3(256 / 32, 4), 64, 0, stream>>>(W1, Bp1, 256);
  k_prep<<<dim3(256 / 32, 4), 64, 0, stream>>>(W2, Bp2, 256);

  dim3 ggrid((N + 63) / 64, 2);
  int nblk = (N + 3) / 4;

  // h0 = relu(xc @ Wp + bp)  -> bf16
  k_mm<28, true, true, false, true><<<ggrid, 256, 0, stream>>>(
      x, BpP, bp, (void*)h0b, nullptr, nullptr, nullptr, nullptr, N);
  // h1 = h0 + sum_in(h0[src] + rel*w)  (f32 out)
  k_agg<<<nblk, 256, 0, stream>>>(h0b, offs, csrc, cet, cw, rel, h1, N);
  // GAT layer 1: xh = h1 @ W1 (bf16 out, fused att projections)
  k_mm<8, false, false, true, true><<<ggrid, 256, 0, stream>>>(
      h1, Bp1, nullptr, (void*)xhb, as1, ad1, aS, aD, N);
  k_gat<false><<<nblk, 256, 0, stream>>>(xhb, aS, aD, offs, csrc, b1, h1, nullptr, nullptr, nullptr, N);
  // GAT layer 2 + fused score
  k_mm<8, false, false, true, true><<<ggrid, 256, 0, stream>>>(
      h1, Bp2, nullptr, (void*)xhb, as2, ad2, aS, aD, N);
  k_gat<true><<<nblk, 256, 0, stream>>>(xhb, aS, aD, offs, csrc, b2, nullptr, Wo, bo, out, N);
}

// Round 7
// 285.554 us; speedup vs baseline: 1.3354x; 1.0152x over previous
//
#include <hip/hip_runtime.h>
#include <hip/hip_bf16.h>

#define N_NODES 20000
#define E_EDGES 320000

typedef __attribute__((ext_vector_type(8))) short s8v;
typedef __attribute__((ext_vector_type(4))) float f4v;

__device__ __forceinline__ float lrelu(float v){ return v > 0.f ? v : 0.2f * v; }

__device__ __forceinline__ float bitf(unsigned short u){
  union { unsigned int i; float f; } v; v.i = ((unsigned int)u) << 16; return v.f;
}
__device__ __forceinline__ float4 bf4(const unsigned short* p){
  ushort4 u = *(const ushort4*)p;
  return make_float4(bitf(u.x), bitf(u.y), bitf(u.z), bitf(u.w));
}
// round-to-nearest-even f32 -> bf16 (bit trick)
__device__ __forceinline__ unsigned short bfhi(float v){
  union{float f; unsigned u;} a; a.f = v;
  unsigned r = a.u + 0x7FFFu + ((a.u >> 16) & 1u);
  return (unsigned short)(r >> 16);
}
__device__ __forceinline__ float bf2f(unsigned short h){
  union{unsigned u; float f;} a; a.u = ((unsigned)h) << 16; return a.f;
}
// split pair (v0,v1) into packed-bf16 hi word and lo word (RNE)
__device__ __forceinline__ void split2(float v0, float v1, unsigned& hu, unsigned& lu){
  __hip_bfloat162 h2 = __float22bfloat162_rn(make_float2(v0, v1));
  unsigned h; __builtin_memcpy(&h, &h2, 4);
  union{unsigned u; float f;} c0, c1;
  c0.u = h << 16;
  c1.u = h & 0xFFFF0000u;
  __hip_bfloat162 l2 = __float22bfloat162_rn(make_float2(v0 - c0.f, v1 - c1.f));
  unsigned l; __builtin_memcpy(&l, &l2, 4);
  hu = h; lu = l;
}

// ---------------- CSR build ----------------
__global__ __launch_bounds__(256) void k_count(const int* __restrict__ dst, int* __restrict__ deg, int E){
  int e = blockIdx.x * 256 + threadIdx.x;
  if (e < E) atomicAdd(&deg[dst[e]], 1);
}

__global__ __launch_bounds__(256) void k_scan(const int* __restrict__ deg, int* __restrict__ off,
                                              int* __restrict__ cur, int n){
  __shared__ int part[256];
  __shared__ int base[257];
  int tid = threadIdx.x;
  int chunk = (n + 255) / 256;
  int st = tid * chunk;
  int en = st + chunk; if (en > n) en = n;
  int s = 0;
  for (int i = st; i < en; ++i) s += deg[i];
  part[tid] = s;
  __syncthreads();
  if (tid == 0){
    int a = 0;
    for (int i = 0; i < 256; ++i){ base[i] = a; a += part[i]; }
    base[256] = a;
  }
  __syncthreads();
  int a = base[tid];
  for (int i = st; i < en; ++i){ off[i] = a; cur[i] = 0; a += deg[i]; }
  if (tid == 0) off[n] = base[256];
}

__global__ __launch_bounds__(256) void k_fill(const int* __restrict__ src, const int* __restrict__ dst,
                       const int* __restrict__ ety, const float* __restrict__ ew,
                       const int* __restrict__ off, int* __restrict__ cur,
                       int* __restrict__ csrc, int* __restrict__ cet, float* __restrict__ cw, int E){
  int e = blockIdx.x * 256 + threadIdx.x;
  if (e < E){
    int d = dst[e];
    int p = atomicAdd(&cur[d], 1);
    int i = off[d] + p;
    csrc[i] = src[e];
    cet[i]  = ety[e];
    cw[i]   = ew[e];
  }
}

// ---------------- weight prep: W[K][256] f32 -> Bp hi/lo bf16, layout [kt][n][32kk] ----------------
__global__ __launch_bounds__(64) void k_prep(const float* __restrict__ W, unsigned short* __restrict__ Bp, int K){
  int kt = blockIdx.x;
  int n  = blockIdx.y * 64 + threadIdx.x;
  unsigned short hi[32], lo[32];
#pragma unroll
  for (int kk = 0; kk < 32; ++kk){
    float v = W[(size_t)(kt * 32 + kk) * 256 + n];   // coalesced over n
    unsigned short h = bfhi(v);
    hi[kk] = h;
    lo[kk] = bfhi(v - bf2f(h));
  }
  size_t plane = (size_t)(K >> 5) * 256 * 32;
  size_t b = ((size_t)kt * 256 + n) * 32;
#pragma unroll
  for (int kk = 0; kk < 32; ++kk){
    Bp[b + kk]         = hi[kk];
    Bp[plane + b + kk] = lo[kk];
  }
}

// ---------------- dbuf split-bf16 MFMA GEMM (BM=64, BN=64, 1 barrier/iter) ----------------
// C[M][256] = A[M][K] @ B.  4 waves (2m x 2n), wave tile 32x32 (2x2 frags, 12 MFMA/iter).
// 1D grid: bx = bid>>2 (row tile), by = bid&3 (col tile / head) -> same-A blocks dispatch-adjacent.
// A: f32, split hi/lo during LDS staging, DOUBLE-buffered; A-prefetch distance = 1 full iter.
// B: pre-split frag-ordered Bp straight from global (L2-hot), register double-buffered.
// ATT: fused a_src/a_dst with cross-wave LDS combine (block's 64 cols = head `by`).
template<int KT, bool PERM, bool EPI, bool ATT, bool CBF>
__global__ __launch_bounds__(256, 4) void k_mm(
    const float* __restrict__ A, const unsigned short* __restrict__ Bp,
    const float* __restrict__ bias, void* __restrict__ Cout,
    const float* __restrict__ attS, const float* __restrict__ attD,
    float* __restrict__ aS, float* __restrict__ aD, int M)
{
  constexpr int K = KT * 32;
  __shared__ unsigned short AhB[2][64 * 40];
  __shared__ unsigned short AlB[2][64 * 40];
  __shared__ float smS[2][2][4][4][2];   // [wm][f][kg][r][wn]
  __shared__ float smD[2][2][4][4][2];

  const int tid  = threadIdx.x;
  const int lane = tid & 63;
  const int w    = tid >> 6;
  const int wm   = w >> 1;
  const int wn   = w & 1;
  const int l15  = lane & 15;
  const int kg   = lane >> 4;
  const int bid  = blockIdx.x;
  const int m0   = (bid >> 2) * 64;
  const int by   = bid & 3;
  const int n0   = by * 64;
  const size_t planeB = (size_t)KT * 256 * 32;

  f4v acc[2][2];
#pragma unroll
  for (int f = 0; f < 2; ++f)
#pragma unroll
    for (int g = 0; g < 2; ++g)
#pragma unroll
      for (int r = 0; r < 4; ++r) acc[f][g][r] = 0.f;

  const int arow = tid >> 2;          // 0..63 staged row
  const int aj   = tid & 3;           // k-chunk: akk = aj*8
  const int gr   = m0 + arow;

  auto loadA = [&](float* v, int kt){
    if (gr < M){
      if constexpr (PERM){
        int c = kt * 32 + aj * 8;     // 8-chunks never straddle c=128
        const float* sp; float sc;
        if (c < 128){ sp = A + (size_t)gr * 896 + (768 + c); sc = 1.f; }
        else        { sp = A + (size_t)gr * 896 + (c - 128); sc = 3.f; }
        float4 f0 = *(const float4*)sp;
        float4 f1 = *(const float4*)(sp + 4);
        v[0]=f0.x*sc; v[1]=f0.y*sc; v[2]=f0.z*sc; v[3]=f0.w*sc;
        v[4]=f1.x*sc; v[5]=f1.y*sc; v[6]=f1.z*sc; v[7]=f1.w*sc;
      } else {
        const float* sp = A + (size_t)gr * K + kt * 32 + aj * 8;
        float4 f0 = *(const float4*)sp;
        float4 f1 = *(const float4*)(sp + 4);
        v[0]=f0.x; v[1]=f0.y; v[2]=f0.z; v[3]=f0.w;
        v[4]=f1.x; v[5]=f1.y; v[6]=f1.z; v[7]=f1.w;
      }
    } else {
#pragma unroll
      for (int j = 0; j < 8; ++j) v[j] = 0.f;
    }
  };
  auto writeLDS = [&](const float* v, int buf){
    union { unsigned u[4]; s8v s; } hv, lv;
#pragma unroll
    for (int p = 0; p < 4; ++p)
      split2(v[2*p], v[2*p+1], hv.u[p], lv.u[p]);
    *(s8v*)&AhB[buf][arow * 40 + aj * 8] = hv.s;
    *(s8v*)&AlB[buf][arow * 40 + aj * 8] = lv.s;
  };
  auto loadB = [&](s8v* bh, s8v* bl, int kt){
#pragma unroll
    for (int g = 0; g < 2; ++g){
      const unsigned short* bp2 = Bp + ((size_t)kt * 256 + n0 + wn * 32 + g * 16 + l15) * 32 + kg * 8;
      bh[g] = *(const s8v*)bp2;
      bl[g] = *(const s8v*)(bp2 + planeB);
    }
  };

  float av[8];
  loadA(av, 0);
  writeLDS(av, 0);
  if (KT > 1) loadA(av, 1);
  s8v bh[2], bl[2];
  loadB(bh, bl, 0);

  int cur = 0;
  for (int kt = 0; kt < KT; ++kt){
    __syncthreads();                       // LDS[cur] ready; LDS[cur^1] free
    if (kt + 1 < KT) writeLDS(av, cur ^ 1);
    if (kt + 2 < KT) loadA(av, kt + 2);
    s8v nbh[2], nbl[2];
    if (kt + 1 < KT) loadB(nbh, nbl, kt + 1);
    // A fragments from LDS[cur]
    s8v ah[2], al[2];
#pragma unroll
    for (int f = 0; f < 2; ++f){
      int row = wm * 32 + f * 16 + l15;
      ah[f] = *(const s8v*)&AhB[cur][row * 40 + kg * 8];
      al[f] = *(const s8v*)&AlB[cur][row * 40 + kg * 8];
    }
#pragma unroll
    for (int f = 0; f < 2; ++f)
#pragma unroll
      for (int g = 0; g < 2; ++g){
        acc[f][g] = __builtin_amdgcn_mfma_f32_16x16x32_bf16(ah[f], bh[g], acc[f][g], 0, 0, 0);
        acc[f][g] = __builtin_amdgcn_mfma_f32_16x16x32_bf16(ah[f], bl[g], acc[f][g], 0, 0, 0);
        acc[f][g] = __builtin_amdgcn_mfma_f32_16x16x32_bf16(al[f], bh[g], acc[f][g], 0, 0, 0);
      }
    if (kt + 1 < KT){
      bh[0] = nbh[0]; bh[1] = nbh[1];
      bl[0] = nbl[0]; bl[1] = nbl[1];
    }
    cur ^= 1;
  }

  // ---- epilogue: D layout col=lane&15, row=(lane>>4)*4+reg ----
#pragma unroll
  for (int f = 0; f < 2; ++f){
#pragma unroll
    for (int g = 0; g < 2; ++g){
      int col = n0 + wn * 32 + g * 16 + l15;
      float bb = EPI ? bias[col] : 0.f;
#pragma unroll
      for (int r = 0; r < 4; ++r){
        int row = m0 + wm * 32 + f * 16 + kg * 4 + r;
        if (row < M){
          float v = acc[f][g][r];
          if constexpr (EPI) v = fmaxf(v + bb, 0.f);
          if constexpr (CBF) ((unsigned short*)Cout)[(size_t)row * 256 + col] = bfhi(v);
          else               ((float*)Cout)[(size_t)row * 256 + col] = v;
        }
      }
    }
  }

  if constexpr (ATT){
    // block's 64 cols == head `by`; cross-wave (wn) combine via LDS
    float sv[2], dv[2];
#pragma unroll
    for (int g = 0; g < 2; ++g){
      int col = n0 + wn * 32 + g * 16 + l15;
      sv[g] = attS[col];
      dv[g] = attD[col];
    }
#pragma unroll
    for (int f = 0; f < 2; ++f){
#pragma unroll
      for (int r = 0; r < 4; ++r){
        float ps = acc[f][0][r]*sv[0] + acc[f][1][r]*sv[1];
        float pd = acc[f][0][r]*dv[0] + acc[f][1][r]*dv[1];
#pragma unroll
        for (int mm = 1; mm < 16; mm <<= 1){
          ps += __shfl_xor(ps, mm, 64);
          pd += __shfl_xor(pd, mm, 64);
        }
        if (l15 == 0){
          smS[wm][f][kg][r][wn] = ps;
          smD[wm][f][kg][r][wn] = pd;
        }
      }
    }
    __syncthreads();
    if (tid < 64){
      int wm2 = tid >> 5, f2 = (tid >> 4) & 1, kg2 = (tid >> 2) & 3, r2 = tid & 3;
      int row = m0 + wm2 * 32 + f2 * 16 + kg2 * 4 + r2;
      if (row < M){
        float s = smS[wm2][f2][kg2][r2][0] + smS[wm2][f2][kg2][r2][1];
        float d = smD[wm2][f2][kg2][r2][0] + smD[wm2][f2][kg2][r2][1];
        aS[(size_t)row * 4 + by] = s;
        aD[(size_t)row * 4 + by] = d;
      }
    }
  }
}

// ---------------- first aggregation: h1 = h0 + sum_e (h0[src] + rel[et]*w); h0 is bf16 ----------------
__global__ __launch_bounds__(256) void k_agg(
    const unsigned short* __restrict__ h0, const int* __restrict__ off,
    const int* __restrict__ csrc, const int* __restrict__ cet, const float* __restrict__ cw,
    const float* __restrict__ rel, float* __restrict__ h1, int N)
{
  int n = blockIdx.x * 4 + (threadIdx.x >> 6);
  if (n >= N) return;
  int lane = threadIdx.x & 63;
  int c0 = lane * 4;
  float4 acc = bf4(&h0[(size_t)n * 256 + c0]);
  int s0 = off[n], s1 = off[n + 1];
  int e = s0;
  for (; e + 3 < s1; e += 4){
    int sA = csrc[e], sB = csrc[e+1], sC = csrc[e+2], sD = csrc[e+3];
    int tA = cet[e],  tB = cet[e+1],  tC = cet[e+2],  tD = cet[e+3];
    float wA = cw[e], wB = cw[e+1], wC = cw[e+2], wD = cw[e+3];
    float4 hA = bf4(&h0[(size_t)sA * 256 + c0]);
    float4 hB = bf4(&h0[(size_t)sB * 256 + c0]);
    float4 hC = bf4(&h0[(size_t)sC * 256 + c0]);
    float4 hD = bf4(&h0[(size_t)sD * 256 + c0]);
    float4 rA = *(const float4*)&rel[(size_t)tA * 256 + c0];
    float4 rB = *(const float4*)&rel[(size_t)tB * 256 + c0];
    float4 rC = *(const float4*)&rel[(size_t)tC * 256 + c0];
    float4 rD = *(const float4*)&rel[(size_t)tD * 256 + c0];
    acc.x += hA.x + hB.x + hC.x + hD.x + rA.x*wA + rB.x*wB + rC.x*wC + rD.x*wD;
    acc.y += hA.y + hB.y + hC.y + hD.y + rA.y*wA + rB.y*wB + rC.y*wC + rD.y*wD;
    acc.z += hA.z + hB.z + hC.z + hD.z + rA.z*wA + rB.z*wB + rC.z*wC + rD.z*wD;
    acc.w += hA.w + hB.w + hC.w + hD.w + rA.w*wA + rB.w*wB + rC.w*wC + rD.w*wD;
  }
  for (; e < s1; ++e){
    int s = csrc[e];
    int t = cet[e];
    float wg = cw[e];
    float4 hv = bf4(&h0[(size_t)s * 256 + c0]);
    float4 rv = *(const float4*)&rel[(size_t)t * 256 + c0];
    acc.x += hv.x + rv.x * wg;
    acc.y += hv.y + rv.y * wg;
    acc.z += hv.z + rv.z * wg;
    acc.w += hv.w + rv.w * wg;
  }
  *(float4*)&h1[(size_t)n * 256 + c0] = acc;
}

// ---------------- GAT edge softmax + aggregate (self-loop included); xh is bf16 ----------------
// SCORE: fold final h@Wo+bo into the layer-2 epilogue, write out[n] instead of hout.
template<bool SCORE>
__global__ __launch_bounds__(256) void k_gat(
    const unsigned short* __restrict__ xh, const float* __restrict__ aS, const float* __restrict__ aD,
    const int* __restrict__ off, const int* __restrict__ csrc,
    const float* __restrict__ bias, float* __restrict__ hout,
    const float* __restrict__ Wo, const float* __restrict__ bo, float* __restrict__ out, int N)
{
  int n = blockIdx.x * 4 + (threadIdx.x >> 6);
  if (n >= N) return;
  int lane = threadIdx.x & 63;
  int head = lane >> 4;
  int c0 = lane * 4;
  int s0 = off[n], s1 = off[n + 1];

  float ad0, ad1, ad2, ad3;
  { float4 t = *(const float4*)&aD[(size_t)n * 4]; ad0 = t.x; ad1 = t.y; ad2 = t.z; ad3 = t.w; }
  float q0, q1, q2, q3;  // running max per head (init with self-loop)
  { float4 t = *(const float4*)&aS[(size_t)n * 4];
    q0 = lrelu(t.x + ad0); q1 = lrelu(t.y + ad1); q2 = lrelu(t.z + ad2); q3 = lrelu(t.w + ad3); }

  for (int base = s0; base < s1; base += 64){
    int e = base + lane;
    if (e < s1){
      int s = csrc[e];
      float4 av = *(const float4*)&aS[(size_t)s * 4];
      q0 = fmaxf(q0, lrelu(av.x + ad0));
      q1 = fmaxf(q1, lrelu(av.y + ad1));
      q2 = fmaxf(q2, lrelu(av.z + ad2));
      q3 = fmaxf(q3, lrelu(av.w + ad3));
    }
  }
#pragma unroll
  for (int mm = 1; mm < 64; mm <<= 1){
    q0 = fmaxf(q0, __shfl_xor(q0, mm, 64));
    q1 = fmaxf(q1, __shfl_xor(q1, mm, 64));
    q2 = fmaxf(q2, __shfl_xor(q2, mm, 64));
    q3 = fmaxf(q3, __shfl_xor(q3, mm, 64));
  }
  float adh = head == 0 ? ad0 : (head == 1 ? ad1 : (head == 2 ? ad2 : ad3));
  float mh  = head == 0 ? q0  : (head == 1 ? q1  : (head == 2 ? q2  : q3));

  float ash = aS[(size_t)n * 4 + head];
  float ex = __expf(lrelu(ash + adh) - mh);
  float den = ex;
  float4 xv = bf4(&xh[(size_t)n * 256 + c0]);
  float4 acc;
  acc.x = ex * xv.x; acc.y = ex * xv.y; acc.z = ex * xv.z; acc.w = ex * xv.w;

  int e = s0;
  for (; e + 3 < s1; e += 4){
    int sA = csrc[e], sB = csrc[e+1], sC = csrc[e+2], sD = csrc[e+3];
    float aA = aS[(size_t)sA * 4 + head];
    float aB = aS[(size_t)sB * 4 + head];
    float aC = aS[(size_t)sC * 4 + head];
    float aD2 = aS[(size_t)sD * 4 + head];
    float4 xA = bf4(&xh[(size_t)sA * 256 + c0]);
    float4 xB = bf4(&xh[(size_t)sB * 256 + c0]);
    float4 xC = bf4(&xh[(size_t)sC * 256 + c0]);
    float4 xD = bf4(&xh[(size_t)sD * 256 + c0]);
    float eA = __expf(lrelu(aA + adh) - mh);
    float eB = __expf(lrelu(aB + adh) - mh);
    float eC = __expf(lrelu(aC + adh) - mh);
    float eD = __expf(lrelu(aD2 + adh) - mh);
    den += eA + eB + eC + eD;
    acc.x = fmaf(eA, xA.x, fmaf(eB, xB.x, fmaf(eC, xC.x, fmaf(eD, xD.x, acc.x))));
    acc.y = fmaf(eA, xA.y, fmaf(eB, xB.y, fmaf(eC, xC.y, fmaf(eD, xD.y, acc.y))));
    acc.z = fmaf(eA, xA.z, fmaf(eB, xB.z, fmaf(eC, xC.z, fmaf(eD, xD.z, acc.z))));
    acc.w = fmaf(eA, xA.w, fmaf(eB, xB.w, fmaf(eC, xC.w, fmaf(eD, xD.w, acc.w))));
  }
  for (; e < s1; ++e){
    int s = csrc[e];
    float a  = aS[(size_t)s * 4 + head];
    float e2 = __expf(lrelu(a + adh) - mh);
    den += e2;
    float4 x2 = bf4(&xh[(size_t)s * 256 + c0]);
    acc.x = fmaf(e2, x2.x, acc.x);
    acc.y = fmaf(e2, x2.y, acc.y);
    acc.z = fmaf(e2, x2.z, acc.z);
    acc.w = fmaf(e2, x2.w, acc.w);
  }
  float inv = 1.f / den;
  float4 bb = *(const float4*)&bias[c0];
  float4 o;
  o.x = acc.x * inv + bb.x;
  o.y = acc.y * inv + bb.y;
  o.z = acc.z * inv + bb.z;
  o.w = acc.w * inv + bb.w;
  if constexpr (SCORE){
    float4 wv = *(const float4*)&Wo[c0];
    float p = o.x * wv.x + o.y * wv.y + o.z * wv.z + o.w * wv.w;
#pragma unroll
    for (int mm = 1; mm < 64; mm <<= 1) p += __shfl_xor(p, mm, 64);
    if (lane == 0) out[n] = p + bo[0];
  } else {
    *(float4*)&hout[(size_t)n * 256 + c0] = o;
  }
}

extern "C" void kernel_launch(void* const* d_in, const int* in_sizes, int n_in,
                              void* d_out, int out_size, void* d_ws, size_t ws_size,
                              hipStream_t stream)
{
  const float* x   = (const float*)d_in[0];
  const int*   ei  = (const int*)  d_in[1];
  const int*   ety = (const int*)  d_in[2];
  const float* ew  = (const float*)d_in[3];
  const float* rel = (const float*)d_in[4];
  const float* Wp  = (const float*)d_in[5];
  const float* bp  = (const float*)d_in[6];
  const float* W1  = (const float*)d_in[7];
  const float* as1 = (const float*)d_in[8];
  const float* ad1 = (const float*)d_in[9];
  const float* b1  = (const float*)d_in[10];
  const float* W2  = (const float*)d_in[11];
  const float* as2 = (const float*)d_in[12];
  const float* ad2 = (const float*)d_in[13];
  const float* b2  = (const float*)d_in[14];
  const float* Wo  = (const float*)d_in[15];
  const float* bo  = (const float*)d_in[16];
  float* out = (float*)d_out;

  const int N = N_NODES, E = E_EDGES;
  char* w = (char*)d_ws;
  size_t o = 0;
  auto alloc = [&](size_t bytes) -> char* {
    char* p = w + o;
    o = (o + bytes + 255) & ~(size_t)255;
    return p;
  };
  unsigned short* h0b = (unsigned short*)alloc((size_t)N * 256 * 2);  // bf16 h0
  unsigned short* xhb = (unsigned short*)alloc((size_t)N * 256 * 2);  // bf16 xh
  float* h1  = (float*)alloc((size_t)N * 256 * 4);
  float* aS  = (float*)alloc((size_t)N * 4 * 4);
  float* aD  = (float*)alloc((size_t)N * 4 * 4);
  int* deg   = (int*)alloc((size_t)N * 4);
  int* offs  = (int*)alloc((size_t)(N + 1) * 4);
  int* cur   = (int*)alloc((size_t)N * 4);
  int* csrc  = (int*)alloc((size_t)E * 4);
  int* cet   = (int*)alloc((size_t)E * 4);
  float* cw  = (float*)alloc((size_t)E * 4);
  unsigned short* BpP = (unsigned short*)alloc((size_t)2 * 896 * 256 * 2);
  unsigned short* Bp1 = (unsigned short*)alloc((size_t)2 * 256 * 256 * 2);
  unsigned short* Bp2 = (unsigned short*)alloc((size_t)2 * 256 * 256 * 2);

  const int* srcp = ei;
  const int* dstp = ei + E;

  hipMemsetAsync(deg, 0, (size_t)N * 4, stream);
  k_count<<<(E + 255) / 256, 256, 0, stream>>>(dstp, deg, E);
  k_scan<<<1, 256, 0, stream>>>(deg, offs, cur, N);
  k_fill<<<(E + 255) / 256, 256, 0, stream>>>(srcp, dstp, ety, ew, offs, cur, csrc, cet, cw, E);

  // weight pre-split into frag-ordered hi/lo planes
  k_prep<<<dim3(896 / 32, 4), 64, 0, stream>>>(Wp, BpP, 896);
  k_prep<<<dim3(256 / 32, 4), 64, 0, stream>>>(W1, Bp1, 256);
  k_prep<<<dim3(256 / 32, 4), 64, 0, stream>>>(W2, Bp2, 256);

  int gblk = ((N + 63) / 64) * 4;   // 1D grid: bx=bid>>2 (rows), by=bid&3 (64-col tile)
  int nblk = (N + 3) / 4;

  // h0 = relu(xc @ Wp + bp)  -> bf16
  k_mm<28, true, true, false, true><<<gblk, 256, 0, stream>>>(
      x, BpP, bp, (void*)h0b, nullptr, nullptr, nullptr, nullptr, N);
  // h1 = h0 + sum_in(h0[src] + rel*w)  (f32 out)
  k_agg<<<nblk, 256, 0, stream>>>(h0b, offs, csrc, cet, cw, rel, h1, N);
  // GAT layer 1: xh = h1 @ W1 (bf16 out, fused att projections)
  k_mm<8, false, false, true, true><<<gblk, 256, 0, stream>>>(
      h1, Bp1, nullptr, (void*)xhb, as1, ad1, aS, aD, N);
  k_gat<false><<<nblk, 256, 0, stream>>>(xhb, aS, aD, offs, csrc, b1, h1, nullptr, nullptr, nullptr, N);
  // GAT layer 2 + fused score
  k_mm<8, false, false, true, true><<<gblk, 256, 0, stream>>>(
      h1, Bp2, nullptr, (void*)xhb, as2, ad2, aS, aD, N);
  k_gat<true><<<nblk, 256, 0, stream>>>(xhb, aS, aD, offs, csrc, b2, nullptr, Wo, bo, out, N);
}

// Round 8
// 272.274 us; speedup vs baseline: 1.4005x; 1.0488x over previous
//
#include <hip/hip_runtime.h>
#include <hip/hip_bf16.h>

#define N_NODES 20000
#define E_EDGES 320000

typedef __attribute__((ext_vector_type(8))) short s8v;
typedef __attribute__((ext_vector_type(4))) float f4v;

__device__ __forceinline__ float lrelu(float v){ return v > 0.f ? v : 0.2f * v; }

__device__ __forceinline__ float bitf(unsigned short u){
  union { unsigned int i; float f; } v; v.i = ((unsigned int)u) << 16; return v.f;
}
__device__ __forceinline__ float4 bf4(const unsigned short* p){
  ushort4 u = *(const ushort4*)p;
  return make_float4(bitf(u.x), bitf(u.y), bitf(u.z), bitf(u.w));
}
// round-to-nearest-even f32 -> bf16 (bit trick)
__device__ __forceinline__ unsigned short bfhi(float v){
  union{float f; unsigned u;} a; a.f = v;
  unsigned r = a.u + 0x7FFFu + ((a.u >> 16) & 1u);
  return (unsigned short)(r >> 16);
}
__device__ __forceinline__ float bf2f(unsigned short h){
  union{unsigned u; float f;} a; a.u = ((unsigned)h) << 16; return a.f;
}
// split pair (v0,v1) into packed-bf16 hi word and lo word (RNE)
__device__ __forceinline__ void split2(float v0, float v1, unsigned& hu, unsigned& lu){
  __hip_bfloat162 h2 = __float22bfloat162_rn(make_float2(v0, v1));
  unsigned h; __builtin_memcpy(&h, &h2, 4);
  union{unsigned u; float f;} c0, c1;
  c0.u = h << 16;
  c1.u = h & 0xFFFF0000u;
  __hip_bfloat162 l2 = __float22bfloat162_rn(make_float2(v0 - c0.f, v1 - c1.f));
  unsigned l; __builtin_memcpy(&l, &l2, 4);
  hu = h; lu = l;
}

// ---------------- CSR build ----------------
__global__ __launch_bounds__(256) void k_count(const int* __restrict__ dst, int* __restrict__ deg, int E){
  int e = blockIdx.x * 256 + threadIdx.x;
  if (e < E) atomicAdd(&deg[dst[e]], 1);
}

__global__ __launch_bounds__(256) void k_scan(const int* __restrict__ deg, int* __restrict__ off,
                                              int* __restrict__ cur, int n){
  __shared__ int part[256];
  __shared__ int base[257];
  int tid = threadIdx.x;
  int chunk = (n + 255) / 256;
  int st = tid * chunk;
  int en = st + chunk; if (en > n) en = n;
  int s = 0;
  for (int i = st; i < en; ++i) s += deg[i];
  part[tid] = s;
  __syncthreads();
  if (tid == 0){
    int a = 0;
    for (int i = 0; i < 256; ++i){ base[i] = a; a += part[i]; }
    base[256] = a;
  }
  __syncthreads();
  int a = base[tid];
  for (int i = st; i < en; ++i){ off[i] = a; cur[i] = 0; a += deg[i]; }
  if (tid == 0) off[n] = base[256];
}

__global__ __launch_bounds__(256) void k_fill(const int* __restrict__ src, const int* __restrict__ dst,
                       const int* __restrict__ ety, const float* __restrict__ ew,
                       const int* __restrict__ off, int* __restrict__ cur,
                       int* __restrict__ csrc, int* __restrict__ cet, float* __restrict__ cw, int E){
  int e = blockIdx.x * 256 + threadIdx.x;
  if (e < E){
    int d = dst[e];
    int p = atomicAdd(&cur[d], 1);
    int i = off[d] + p;
    csrc[i] = src[e];
    cet[i]  = ety[e];
    cw[i]   = ew[e];
  }
}

// ---------------- weight prep: W[K][256] f32 -> Bp hi/lo bf16, layout [kt][n][32kk] ----------------
__global__ __launch_bounds__(64) void k_prep(const float* __restrict__ W, unsigned short* __restrict__ Bp, int K){
  int kt = blockIdx.x;
  int n  = blockIdx.y * 64 + threadIdx.x;
  unsigned short hi[32], lo[32];
#pragma unroll
  for (int kk = 0; kk < 32; ++kk){
    float v = W[(size_t)(kt * 32 + kk) * 256 + n];   // coalesced over n
    unsigned short h = bfhi(v);
    hi[kk] = h;
    lo[kk] = bfhi(v - bf2f(h));
  }
  size_t plane = (size_t)(K >> 5) * 256 * 32;
  size_t b = ((size_t)kt * 256 + n) * 32;
#pragma unroll
  for (int kk = 0; kk < 32; ++kk){
    Bp[b + kk]         = hi[kk];
    Bp[plane + b + kk] = lo[kk];
  }
}

// ---------------- dbuf split-bf16 MFMA GEMM (BM=32, BN=128, 2 waves, 1 barrier/iter) ----------------
// C[M][256] = A[M][K] @ B.  128 threads = 2 waves; wave wn: rows m0..m0+31, cols n0+wn*64..+63.
// 24 MFMA per wave per K-step (vs 12 in R7) -> higher MFMA density per barrier.
// 2D x-major grid (625, 2): full A pass for by=0 completes before by=1 -> L3 retains A (R6 behavior).
// A: f32, hi/lo split during LDS staging, double-buffered, prefetch distance 1 iter.
// B: pre-split frag-ordered Bp straight from global (L2-hot).
// ATT: wave's 64 cols == one head (head = by*2 + wn), no cross-wave combine.
template<int KT, bool PERM, bool EPI, bool ATT, bool CBF>
__global__ __launch_bounds__(128, 4) void k_mm(
    const float* __restrict__ A, const unsigned short* __restrict__ Bp,
    const float* __restrict__ bias, void* __restrict__ Cout,
    const float* __restrict__ attS, const float* __restrict__ attD,
    float* __restrict__ aS, float* __restrict__ aD, int M)
{
  constexpr int K = KT * 32;
  __shared__ unsigned short AhB[2][32 * 40];
  __shared__ unsigned short AlB[2][32 * 40];

  const int tid  = threadIdx.x;
  const int lane = tid & 63;
  const int wn   = tid >> 6;
  const int l15  = lane & 15;
  const int kg   = lane >> 4;
  const int m0   = blockIdx.x * 32;
  const int n0   = blockIdx.y * 128;
  const size_t planeB = (size_t)KT * 256 * 32;

  f4v acc[2][4];
#pragma unroll
  for (int f = 0; f < 2; ++f)
#pragma unroll
    for (int g = 0; g < 4; ++g)
#pragma unroll
      for (int r = 0; r < 4; ++r) acc[f][g][r] = 0.f;

  const int arow = tid >> 2;          // 0..31 staged row
  const int aj   = tid & 3;           // k-chunk: akk = aj*8
  const int gr   = m0 + arow;

  auto loadA = [&](float* v, int kt){
    if (gr < M){
      if constexpr (PERM){
        int c = kt * 32 + aj * 8;     // 8-chunks never straddle c=128
        const float* sp; float sc;
        if (c < 128){ sp = A + (size_t)gr * 896 + (768 + c); sc = 1.f; }
        else        { sp = A + (size_t)gr * 896 + (c - 128); sc = 3.f; }
        float4 f0 = *(const float4*)sp;
        float4 f1 = *(const float4*)(sp + 4);
        v[0]=f0.x*sc; v[1]=f0.y*sc; v[2]=f0.z*sc; v[3]=f0.w*sc;
        v[4]=f1.x*sc; v[5]=f1.y*sc; v[6]=f1.z*sc; v[7]=f1.w*sc;
      } else {
        const float* sp = A + (size_t)gr * K + kt * 32 + aj * 8;
        float4 f0 = *(const float4*)sp;
        float4 f1 = *(const float4*)(sp + 4);
        v[0]=f0.x; v[1]=f0.y; v[2]=f0.z; v[3]=f0.w;
        v[4]=f1.x; v[5]=f1.y; v[6]=f1.z; v[7]=f1.w;
      }
    } else {
#pragma unroll
      for (int j = 0; j < 8; ++j) v[j] = 0.f;
    }
  };
  auto writeLDS = [&](const float* v, int buf){
    union { unsigned u[4]; s8v s; } hv, lv;
#pragma unroll
    for (int p = 0; p < 4; ++p)
      split2(v[2*p], v[2*p+1], hv.u[p], lv.u[p]);
    *(s8v*)&AhB[buf][arow * 40 + aj * 8] = hv.s;
    *(s8v*)&AlB[buf][arow * 40 + aj * 8] = lv.s;
  };

  float av[8];
  loadA(av, 0);
  writeLDS(av, 0);
  if (KT > 1) loadA(av, 1);

  int cur = 0;
  for (int kt = 0; kt < KT; ++kt){
    __syncthreads();                       // LDS[cur] ready; LDS[cur^1] free
    if (kt + 1 < KT) writeLDS(av, cur ^ 1);
    if (kt + 2 < KT) loadA(av, kt + 2);
    // B fragments straight from global (frag-ordered, L2-hot)
    s8v bh[4], bl[4];
#pragma unroll
    for (int g = 0; g < 4; ++g){
      const unsigned short* bp2 = Bp + ((size_t)kt * 256 + n0 + wn * 64 + g * 16 + l15) * 32 + kg * 8;
      bh[g] = *(const s8v*)bp2;
      bl[g] = *(const s8v*)(bp2 + planeB);
    }
    // A fragments from LDS[cur]
    s8v ah[2], al[2];
#pragma unroll
    for (int f = 0; f < 2; ++f){
      int row = f * 16 + l15;
      ah[f] = *(const s8v*)&AhB[cur][row * 40 + kg * 8];
      al[f] = *(const s8v*)&AlB[cur][row * 40 + kg * 8];
    }
#pragma unroll
    for (int f = 0; f < 2; ++f)
#pragma unroll
      for (int g = 0; g < 4; ++g){
        acc[f][g] = __builtin_amdgcn_mfma_f32_16x16x32_bf16(ah[f], bh[g], acc[f][g], 0, 0, 0);
        acc[f][g] = __builtin_amdgcn_mfma_f32_16x16x32_bf16(ah[f], bl[g], acc[f][g], 0, 0, 0);
        acc[f][g] = __builtin_amdgcn_mfma_f32_16x16x32_bf16(al[f], bh[g], acc[f][g], 0, 0, 0);
      }
    cur ^= 1;
  }

  // ---- epilogue: D layout col=lane&15, row=(lane>>4)*4+reg ----
#pragma unroll
  for (int f = 0; f < 2; ++f){
#pragma unroll
    for (int g = 0; g < 4; ++g){
      int col = n0 + wn * 64 + g * 16 + l15;
      float bb = EPI ? bias[col] : 0.f;
#pragma unroll
      for (int r = 0; r < 4; ++r){
        int row = m0 + f * 16 + kg * 4 + r;
        if (row < M){
          float v = acc[f][g][r];
          if constexpr (EPI) v = fmaxf(v + bb, 0.f);
          if constexpr (CBF) ((unsigned short*)Cout)[(size_t)row * 256 + col] = bfhi(v);
          else               ((float*)Cout)[(size_t)row * 256 + col] = v;
        }
      }
    }
  }

  if constexpr (ATT){
    // wave's 64 cols == one head
    const int head = blockIdx.y * 2 + wn;
    float sv[4], dv[4];
#pragma unroll
    for (int g = 0; g < 4; ++g){
      int col = n0 + wn * 64 + g * 16 + l15;
      sv[g] = attS[col];
      dv[g] = attD[col];
    }
#pragma unroll
    for (int f = 0; f < 2; ++f){
#pragma unroll
      for (int r = 0; r < 4; ++r){
        float ps = acc[f][0][r]*sv[0] + acc[f][1][r]*sv[1] + acc[f][2][r]*sv[2] + acc[f][3][r]*sv[3];
        float pd = acc[f][0][r]*dv[0] + acc[f][1][r]*dv[1] + acc[f][2][r]*dv[2] + acc[f][3][r]*dv[3];
#pragma unroll
        for (int mm = 1; mm < 16; mm <<= 1){
          ps += __shfl_xor(ps, mm, 64);
          pd += __shfl_xor(pd, mm, 64);
        }
        int row = m0 + f * 16 + kg * 4 + r;
        if (l15 == 0 && row < M){
          aS[(size_t)row * 4 + head] = ps;
          aD[(size_t)row * 4 + head] = pd;
        }
      }
    }
  }
}

// ---------------- first aggregation: h1 = h0 + sum_e (h0[src] + rel[et]*w); h0 is bf16 ----------------
__global__ __launch_bounds__(256) void k_agg(
    const unsigned short* __restrict__ h0, const int* __restrict__ off,
    const int* __restrict__ csrc, const int* __restrict__ cet, const float* __restrict__ cw,
    const float* __restrict__ rel, float* __restrict__ h1, int N)
{
  int n = blockIdx.x * 4 + (threadIdx.x >> 6);
  if (n >= N) return;
  int lane = threadIdx.x & 63;
  int c0 = lane * 4;
  float4 acc = bf4(&h0[(size_t)n * 256 + c0]);
  int s0 = off[n], s1 = off[n + 1];
  int e = s0;
  for (; e + 3 < s1; e += 4){
    int sA = csrc[e], sB = csrc[e+1], sC = csrc[e+2], sD = csrc[e+3];
    int tA = cet[e],  tB = cet[e+1],  tC = cet[e+2],  tD = cet[e+3];
    float wA = cw[e], wB = cw[e+1], wC = cw[e+2], wD = cw[e+3];
    float4 hA = bf4(&h0[(size_t)sA * 256 + c0]);
    float4 hB = bf4(&h0[(size_t)sB * 256 + c0]);
    float4 hC = bf4(&h0[(size_t)sC * 256 + c0]);
    float4 hD = bf4(&h0[(size_t)sD * 256 + c0]);
    float4 rA = *(const float4*)&rel[(size_t)tA * 256 + c0];
    float4 rB = *(const float4*)&rel[(size_t)tB * 256 + c0];
    float4 rC = *(const float4*)&rel[(size_t)tC * 256 + c0];
    float4 rD = *(const float4*)&rel[(size_t)tD * 256 + c0];
    acc.x += hA.x + hB.x + hC.x + hD.x + rA.x*wA + rB.x*wB + rC.x*wC + rD.x*wD;
    acc.y += hA.y + hB.y + hC.y + hD.y + rA.y*wA + rB.y*wB + rC.y*wC + rD.y*wD;
    acc.z += hA.z + hB.z + hC.z + hD.z + rA.z*wA + rB.z*wB + rC.z*wC + rD.z*wD;
    acc.w += hA.w + hB.w + hC.w + hD.w + rA.w*wA + rB.w*wB + rC.w*wC + rD.w*wD;
  }
  for (; e < s1; ++e){
    int s = csrc[e];
    int t = cet[e];
    float wg = cw[e];
    float4 hv = bf4(&h0[(size_t)s * 256 + c0]);
    float4 rv = *(const float4*)&rel[(size_t)t * 256 + c0];
    acc.x += hv.x + rv.x * wg;
    acc.y += hv.y + rv.y * wg;
    acc.z += hv.z + rv.z * wg;
    acc.w += hv.w + rv.w * wg;
  }
  *(float4*)&h1[(size_t)n * 256 + c0] = acc;
}

// ---------------- GAT edge softmax + aggregate; xh is bf16 ----------------
// Pass 1 (edge-parallel): max per head; cache src + alpha4 in LDS (<=128 edges).
// Pass 1.5 (edge-parallel): alpha->exp in LDS, tree-reduce denominator.
// Pass 2 (serial): LDS ex + xh gather + fma only.  Overflow edges (deg>128): old serial path.
// Wave-local LDS coherence via s_waitcnt lgkmcnt(0) (no block barrier).
// SCORE: fold final h@Wo+bo into epilogue.
template<bool SCORE>
__global__ __launch_bounds__(256) void k_gat(
    const unsigned short* __restrict__ xh, const float* __restrict__ aS, const float* __restrict__ aD,
    const int* __restrict__ off, const int* __restrict__ csrc,
    const float* __restrict__ bias, float* __restrict__ hout,
    const float* __restrict__ Wo, const float* __restrict__ bo, float* __restrict__ out, int N)
{
  __shared__ float4 exs[4][128];
  __shared__ int   srcs[4][128];
  const int wv   = threadIdx.x >> 6;
  const int n    = blockIdx.x * 4 + wv;
  if (n >= N) return;                 // N % 4 == 0: never taken, safe for LDS locality
  const int lane = threadIdx.x & 63;
  const int head = lane >> 4;
  const int c0   = lane * 4;
  const int s0 = off[n], s1 = off[n + 1];
  const int deg = s1 - s0;
  const int nc = deg < 128 ? deg : 128;

  float4 ad4 = *(const float4*)&aD[(size_t)n * 4];
  float4 asf = *(const float4*)&aS[(size_t)n * 4];
  float4 aself;
  aself.x = lrelu(asf.x + ad4.x); aself.y = lrelu(asf.y + ad4.y);
  aself.z = lrelu(asf.z + ad4.z); aself.w = lrelu(asf.w + ad4.w);
  float4 q = aself;                    // running max per head

  // pass 1: max over all edges; cache src+alpha for first 128
  for (int base = 0; base < deg; base += 64){
    int ci = base + lane;
    if (ci < deg){
      int s = csrc[s0 + ci];
      float4 av = *(const float4*)&aS[(size_t)s * 4];
      float4 al4;
      al4.x = lrelu(av.x + ad4.x); al4.y = lrelu(av.y + ad4.y);
      al4.z = lrelu(av.z + ad4.z); al4.w = lrelu(av.w + ad4.w);
      q.x = fmaxf(q.x, al4.x); q.y = fmaxf(q.y, al4.y);
      q.z = fmaxf(q.z, al4.z); q.w = fmaxf(q.w, al4.w);
      if (ci < 128){ srcs[wv][ci] = s; exs[wv][ci] = al4; }
    }
  }
#pragma unroll
  for (int mm = 1; mm < 64; mm <<= 1){
    q.x = fmaxf(q.x, __shfl_xor(q.x, mm, 64));
    q.y = fmaxf(q.y, __shfl_xor(q.y, mm, 64));
    q.z = fmaxf(q.z, __shfl_xor(q.z, mm, 64));
    q.w = fmaxf(q.w, __shfl_xor(q.w, mm, 64));
  }
  asm volatile("s_waitcnt lgkmcnt(0)" ::: "memory");   // pass-1 LDS writes visible in-wave

  // pass 1.5: alpha -> exp in LDS; denominator tree-reduce
  float4 den4 = make_float4(0.f, 0.f, 0.f, 0.f);
  for (int ci = lane; ci < nc; ci += 64){
    float4 a = exs[wv][ci];
    float4 e4;
    e4.x = __expf(a.x - q.x); e4.y = __expf(a.y - q.y);
    e4.z = __expf(a.z - q.z); e4.w = __expf(a.w - q.w);
    exs[wv][ci] = e4;
    den4.x += e4.x; den4.y += e4.y; den4.z += e4.z; den4.w += e4.w;
  }
#pragma unroll
  for (int mm = 1; mm < 64; mm <<= 1){
    den4.x += __shfl_xor(den4.x, mm, 64);
    den4.y += __shfl_xor(den4.y, mm, 64);
    den4.z += __shfl_xor(den4.z, mm, 64);
    den4.w += __shfl_xor(den4.w, mm, 64);
  }
  asm volatile("s_waitcnt lgkmcnt(0)" ::: "memory");   // ex writes visible in-wave

  const float mh  = head == 0 ? q.x : (head == 1 ? q.y : (head == 2 ? q.z : q.w));
  const float adh = head == 0 ? ad4.x : (head == 1 ? ad4.y : (head == 2 ? ad4.z : ad4.w));
  const float aselfh = head == 0 ? aself.x : (head == 1 ? aself.y : (head == 2 ? aself.z : aself.w));
  float den = (head == 0 ? den4.x : (head == 1 ? den4.y : (head == 2 ? den4.z : den4.w)));
  float exself = __expf(aselfh - mh);
  den += exself;

  // pass 2: serial accumulate (LDS ex + xh gather only)
  float4 xv = bf4(&xh[(size_t)n * 256 + c0]);
  float4 acc;
  acc.x = exself * xv.x; acc.y = exself * xv.y; acc.z = exself * xv.z; acc.w = exself * xv.w;

  const float* exw = (const float*)&exs[wv][0];
  int e = 0;
  for (; e + 3 < nc; e += 4){
    int sA = srcs[wv][e], sB = srcs[wv][e+1], sC = srcs[wv][e+2], sD = srcs[wv][e+3];
    float eA = exw[(e  ) * 4 + head];
    float eB = exw[(e+1) * 4 + head];
    float eC = exw[(e+2) * 4 + head];
    float eD = exw[(e+3) * 4 + head];
    float4 xA = bf4(&xh[(size_t)sA * 256 + c0]);
    float4 xB = bf4(&xh[(size_t)sB * 256 + c0]);
    float4 xC = bf4(&xh[(size_t)sC * 256 + c0]);
    float4 xD = bf4(&xh[(size_t)sD * 256 + c0]);
    acc.x = fmaf(eA, xA.x, fmaf(eB, xB.x, fmaf(eC, xC.x, fmaf(eD, xD.x, acc.x))));
    acc.y = fmaf(eA, xA.y, fmaf(eB, xB.y, fmaf(eC, xC.y, fmaf(eD, xD.y, acc.y))));
    acc.z = fmaf(eA, xA.z, fmaf(eB, xB.z, fmaf(eC, xC.z, fmaf(eD, xD.z, acc.z))));
    acc.w = fmaf(eA, xA.w, fmaf(eB, xB.w, fmaf(eC, xC.w, fmaf(eD, xD.w, acc.w))));
  }
  for (; e < nc; ++e){
    int s = srcs[wv][e];
    float ef = exw[e * 4 + head];
    float4 x2 = bf4(&xh[(size_t)s * 256 + c0]);
    acc.x = fmaf(ef, x2.x, acc.x);
    acc.y = fmaf(ef, x2.y, acc.y);
    acc.z = fmaf(ef, x2.z, acc.z);
    acc.w = fmaf(ef, x2.w, acc.w);
  }
  // overflow edges (deg > 128): old serial path, den included
  for (int ci = 128; ci < deg; ++ci){
    int s = csrc[s0 + ci];
    float a  = aS[(size_t)s * 4 + head];
    float ef = __expf(lrelu(a + adh) - mh);
    den += ef;
    float4 x2 = bf4(&xh[(size_t)s * 256 + c0]);
    acc.x = fmaf(ef, x2.x, acc.x);
    acc.y = fmaf(ef, x2.y, acc.y);
    acc.z = fmaf(ef, x2.z, acc.z);
    acc.w = fmaf(ef, x2.w, acc.w);
  }

  float inv = 1.f / den;
  float4 bb = *(const float4*)&bias[c0];
  float4 o;
  o.x = acc.x * inv + bb.x;
  o.y = acc.y * inv + bb.y;
  o.z = acc.z * inv + bb.z;
  o.w = acc.w * inv + bb.w;
  if constexpr (SCORE){
    float4 wvv = *(const float4*)&Wo[c0];
    float p = o.x * wvv.x + o.y * wvv.y + o.z * wvv.z + o.w * wvv.w;
#pragma unroll
    for (int mm = 1; mm < 64; mm <<= 1) p += __shfl_xor(p, mm, 64);
    if (lane == 0) out[n] = p + bo[0];
  } else {
    *(float4*)&hout[(size_t)n * 256 + c0] = o;
  }
}

extern "C" void kernel_launch(void* const* d_in, const int* in_sizes, int n_in,
                              void* d_out, int out_size, void* d_ws, size_t ws_size,
                              hipStream_t stream)
{
  const float* x   = (const float*)d_in[0];
  const int*   ei  = (const int*)  d_in[1];
  const int*   ety = (const int*)  d_in[2];
  const float* ew  = (const float*)d_in[3];
  const float* rel = (const float*)d_in[4];
  const float* Wp  = (const float*)d_in[5];
  const float* bp  = (const float*)d_in[6];
  const float* W1  = (const float*)d_in[7];
  const float* as1 = (const float*)d_in[8];
  const float* ad1 = (const float*)d_in[9];
  const float* b1  = (const float*)d_in[10];
  const float* W2  = (const float*)d_in[11];
  const float* as2 = (const float*)d_in[12];
  const float* ad2 = (const float*)d_in[13];
  const float* b2  = (const float*)d_in[14];
  const float* Wo  = (const float*)d_in[15];
  const float* bo  = (const float*)d_in[16];
  float* out = (float*)d_out;

  const int N = N_NODES, E = E_EDGES;
  char* w = (char*)d_ws;
  size_t o = 0;
  auto alloc = [&](size_t bytes) -> char* {
    char* p = w + o;
    o = (o + bytes + 255) & ~(size_t)255;
    return p;
  };
  unsigned short* h0b = (unsigned short*)alloc((size_t)N * 256 * 2);  // bf16 h0
  unsigned short* xhb = (unsigned short*)alloc((size_t)N * 256 * 2);  // bf16 xh
  float* h1  = (float*)alloc((size_t)N * 256 * 4);
  float* aS  = (float*)alloc((size_t)N * 4 * 4);
  float* aD  = (float*)alloc((size_t)N * 4 * 4);
  int* deg   = (int*)alloc((size_t)N * 4);
  int* offs  = (int*)alloc((size_t)(N + 1) * 4);
  int* cur   = (int*)alloc((size_t)N * 4);
  int* csrc  = (int*)alloc((size_t)E * 4);
  int* cet   = (int*)alloc((size_t)E * 4);
  float* cw  = (float*)alloc((size_t)E * 4);
  unsigned short* BpP = (unsigned short*)alloc((size_t)2 * 896 * 256 * 2);
  unsigned short* Bp1 = (unsigned short*)alloc((size_t)2 * 256 * 256 * 2);
  unsigned short* Bp2 = (unsigned short*)alloc((size_t)2 * 256 * 256 * 2);

  const int* srcp = ei;
  const int* dstp = ei + E;

  hipMemsetAsync(deg, 0, (size_t)N * 4, stream);
  k_count<<<(E + 255) / 256, 256, 0, stream>>>(dstp, deg, E);
  k_scan<<<1, 256, 0, stream>>>(deg, offs, cur, N);
  k_fill<<<(E + 255) / 256, 256, 0, stream>>>(srcp, dstp, ety, ew, offs, cur, csrc, cet, cw, E);

  // weight pre-split into frag-ordered hi/lo planes
  k_prep<<<dim3(896 / 32, 4), 64, 0, stream>>>(Wp, BpP, 896);
  k_prep<<<dim3(256 / 32, 4), 64, 0, stream>>>(W1, Bp1, 256);
  k_prep<<<dim3(256 / 32, 4), 64, 0, stream>>>(W2, Bp2, 256);

  dim3 gg((N + 31) / 32, 2);   // x-major: by=1 re-reads A after full pass -> L3-resident
  int nblk = (N + 3) / 4;

  // h0 = relu(xc @ Wp + bp)  -> bf16
  k_mm<28, true, true, false, true><<<gg, 128, 0, stream>>>(
      x, BpP, bp, (void*)h0b, nullptr, nullptr, nullptr, nullptr, N);
  // h1 = h0 + sum_in(h0[src] + rel*w)  (f32 out)
  k_agg<<<nblk, 256, 0, stream>>>(h0b, offs, csrc, cet, cw, rel, h1, N);
  // GAT layer 1: xh = h1 @ W1 (bf16 out, fused att projections)
  k_mm<8, false, false, true, true><<<gg, 128, 0, stream>>>(
      h1, Bp1, nullptr, (void*)xhb, as1, ad1, aS, aD, N);
  k_gat<false><<<nblk, 256, 0, stream>>>(xhb, aS, aD, offs, csrc, b1, h1, nullptr, nullptr, nullptr, N);
  // GAT layer 2 + fused score
  k_mm<8, false, false, true, true><<<gg, 128, 0, stream>>>(
      h1, Bp2, nullptr, (void*)xhb, as2, ad2, aS, aD, N);
  k_gat<true><<<nblk, 256, 0, stream>>>(xhb, aS, aD, offs, csrc, b2, nullptr, Wo, bo, out, N);
}